// Round 3
// baseline (31411.139 us; speedup 1.0000x reference)
//
#include <hip/hip_runtime.h>
#include <hip/hip_cooperative_groups.h>
#include <math.h>

namespace cg = cooperative_groups;

#define B_ 32
#define T_ 64
#define S_ 256
#define H_ 1024
#define E_ 512
#define BH_ (B_ * H_)
#define GRID_ 512

__device__ __forceinline__ float sigm(float x) {
    return 1.0f / (1.0f + __expf(-x));
}
__device__ __forceinline__ float tanh_(float x) {
    x = fminf(15.0f, fmaxf(-15.0f, x));
    float e = __expf(-2.0f * x);
    return (1.0f - e) / (1.0f + e);
}

struct Params {
    const int* tgt; const float* mem; const int* masks;
    const float* h0in; const float* c0in; const float* emb;
    const float* w_ih0; const float* w_hh0; const float* b_ih0; const float* b_hh0;
    const float* w_ih1; const float* w_hh1; const float* b_ih1; const float* b_hh1;
    const float* w_in; const float* w_out;
    float* dout; float* attn;
    float* h0s; float* h1s; float* feed; float* qbuf; float* scw; float* ctxb;
    int* len;
};

// ===========================================================================
// Persistent cooperative decoder: all 64 timesteps, 6 grid.sync() per step.
// 512 blocks x 256 threads, 2 blocks/CU.  Phase bodies == round-2 kernels.
// ===========================================================================
__global__ __launch_bounds__(256, 2) void k_decoder(Params p) {
    cg::grid_group grid = cg::this_grid();

    __shared__ union {
        struct { float As[4][32][68]; float red[3][64][4]; } gm;  // GEMM phases
        struct { float q_lds[1024]; } sc;                          // scores
        struct { float aw[256]; float red2[4][64]; } cx;           // ctx
    } sh;
    __shared__ int tok[32];

    const int bid  = blockIdx.x;
    const int tid  = threadIdx.x;
    const int b    = tid & 31;
    const int jl   = (tid >> 5) & 1;
    const int ks   = tid >> 6;
    const int j    = bid * 2 + jl;
    const int lane = tid & 63;
    const int wv   = tid >> 6;
    const int idx  = tid & 63;

    // ---------------- init (replaces k_init + per-step mask reduce) --------
    {
        int gid = bid * 256 + tid;
        if (gid < BH_) {
            p.h0s[gid]  = p.h0in[gid];
            p.h1s[gid]  = p.h0in[BH_ + gid];
            p.feed[gid] = 0.0f;
        }
        if (bid < B_ && wv == 0) {
            int m = 0;
            #pragma unroll
            for (int i = 0; i < 4; ++i) m += p.masks[bid * S_ + lane * 4 + i];
            #pragma unroll
            for (int o = 32; o > 0; o >>= 1) m += __shfl_down(m, o);
            if (lane == 0) p.len[bid] = m;
        }
    }
    // cell state + fused biases live in registers for the whole sequence
    float c0_reg = 0.0f, c1_reg = 0.0f;
    float bia0[4] = {0.f, 0.f, 0.f, 0.f}, bia1[4] = {0.f, 0.f, 0.f, 0.f};
    if (ks == 0) {
        c0_reg = p.c0in[b * H_ + j];
        c1_reg = p.c0in[BH_ + b * H_ + j];
        #pragma unroll
        for (int gg = 0; gg < 4; ++gg) {
            bia0[gg] = p.b_ih0[gg * H_ + j] + p.b_hh0[gg * H_ + j];
            bia1[gg] = p.b_ih1[gg * H_ + j] + p.b_hh1[gg * H_ + j];
        }
    }
    grid.sync();

    for (int t = 0; t < T_; ++t) {
        const int cur = t & 1, nxt = cur ^ 1;
        const float* __restrict__ feedc = p.feed + cur * BH_;
        float*       __restrict__ feedn = p.feed + nxt * BH_;
        const float* __restrict__ h0c   = p.h0s + cur * BH_;
        float*       __restrict__ h0n   = p.h0s + nxt * BH_;
        const float* __restrict__ h1c   = p.h1s + cur * BH_;
        float*       __restrict__ h1n   = p.h1s + nxt * BH_;

        // ==================== LSTM0 ====================
        if (tid < 32) tok[tid] = p.tgt[tid * T_ + t];
        __syncthreads();
        {
            float acc0 = bia0[0], acc1 = bia0[1], acc2 = bia0[2], acc3 = bia0[3];
            for (int c = 0; c < 10; ++c) {
                #pragma unroll
                for (int i = 0; i < 8; ++i) {
                    int q   = tid + i * 256;
                    int ksq = q >> 9;
                    int rem = q & 511;
                    int bb  = rem >> 4;
                    int kq  = rem & 15;
                    int kg  = ksq * 640 + c * 64 + kq * 4;
                    const float* src;
                    if (kg < 512)        src = p.emb + (size_t)tok[bb] * E_ + kg;
                    else if (kg < 1536)  src = feedc + (size_t)bb * H_ + (kg - 512);
                    else                 src = h0c + (size_t)bb * H_ + (kg - 1536);
                    *(float4*)&sh.gm.As[ksq][bb][kq * 4] = *(const float4*)src;
                }
                __syncthreads();

                int kbase = ks * 640 + c * 64;
                const float4 *w0, *w1, *w2, *w3;
                if (kbase < 1536) {
                    w0 = (const float4*)(p.w_ih0 + (size_t)(0 * H_ + j) * 1536 + kbase);
                    w1 = (const float4*)(p.w_ih0 + (size_t)(1 * H_ + j) * 1536 + kbase);
                    w2 = (const float4*)(p.w_ih0 + (size_t)(2 * H_ + j) * 1536 + kbase);
                    w3 = (const float4*)(p.w_ih0 + (size_t)(3 * H_ + j) * 1536 + kbase);
                } else {
                    int kb = kbase - 1536;
                    w0 = (const float4*)(p.w_hh0 + (size_t)(0 * H_ + j) * 1024 + kb);
                    w1 = (const float4*)(p.w_hh0 + (size_t)(1 * H_ + j) * 1024 + kb);
                    w2 = (const float4*)(p.w_hh0 + (size_t)(2 * H_ + j) * 1024 + kb);
                    w3 = (const float4*)(p.w_hh0 + (size_t)(3 * H_ + j) * 1024 + kb);
                }
                const float4* A4 = (const float4*)&sh.gm.As[ks][b][0];
                #pragma unroll
                for (int kk = 0; kk < 16; ++kk) {
                    float4 a  = A4[kk];
                    float4 q0 = w0[kk], q1 = w1[kk], q2 = w2[kk], q3 = w3[kk];
                    acc0 += a.x * q0.x + a.y * q0.y + a.z * q0.z + a.w * q0.w;
                    acc1 += a.x * q1.x + a.y * q1.y + a.z * q1.z + a.w * q1.w;
                    acc2 += a.x * q2.x + a.y * q2.y + a.z * q2.z + a.w * q2.w;
                    acc3 += a.x * q3.x + a.y * q3.y + a.z * q3.z + a.w * q3.w;
                }
                __syncthreads();
            }
            if (ks > 0) {
                sh.gm.red[ks - 1][idx][0] = acc0; sh.gm.red[ks - 1][idx][1] = acc1;
                sh.gm.red[ks - 1][idx][2] = acc2; sh.gm.red[ks - 1][idx][3] = acc3;
            }
            __syncthreads();
            if (ks == 0) {
                #pragma unroll
                for (int r = 0; r < 3; ++r) {
                    acc0 += sh.gm.red[r][idx][0]; acc1 += sh.gm.red[r][idx][1];
                    acc2 += sh.gm.red[r][idx][2]; acc3 += sh.gm.red[r][idx][3];
                }
                float cn = sigm(acc1) * c0_reg + sigm(acc0) * tanh_(acc2);
                c0_reg = cn;
                h0n[b * H_ + j] = sigm(acc3) * tanh_(cn);
            }
        }
        grid.sync();

        // ==================== LSTM1 ====================
        {
            float acc0 = bia1[0], acc1 = bia1[1], acc2 = bia1[2], acc3 = bia1[3];
            for (int c = 0; c < 8; ++c) {
                #pragma unroll
                for (int i = 0; i < 8; ++i) {
                    int q   = tid + i * 256;
                    int ksq = q >> 9;
                    int rem = q & 511;
                    int bb  = rem >> 4;
                    int kq  = rem & 15;
                    int kg  = ksq * 512 + c * 64 + kq * 4;
                    const float* src = (kg < 1024) ? (h0n + (size_t)bb * H_ + kg)
                                                   : (h1c + (size_t)bb * H_ + (kg - 1024));
                    *(float4*)&sh.gm.As[ksq][bb][kq * 4] = *(const float4*)src;
                }
                __syncthreads();

                int kbase = ks * 512 + c * 64;
                const float* wb;
                int ko;
                if (kbase < 1024) { wb = p.w_ih1; ko = kbase; }
                else              { wb = p.w_hh1; ko = kbase - 1024; }
                const float4* w0 = (const float4*)(wb + (size_t)(0 * H_ + j) * H_ + ko);
                const float4* w1 = (const float4*)(wb + (size_t)(1 * H_ + j) * H_ + ko);
                const float4* w2 = (const float4*)(wb + (size_t)(2 * H_ + j) * H_ + ko);
                const float4* w3 = (const float4*)(wb + (size_t)(3 * H_ + j) * H_ + ko);
                const float4* A4 = (const float4*)&sh.gm.As[ks][b][0];
                #pragma unroll
                for (int kk = 0; kk < 16; ++kk) {
                    float4 a  = A4[kk];
                    float4 q0 = w0[kk], q1 = w1[kk], q2 = w2[kk], q3 = w3[kk];
                    acc0 += a.x * q0.x + a.y * q0.y + a.z * q0.z + a.w * q0.w;
                    acc1 += a.x * q1.x + a.y * q1.y + a.z * q1.z + a.w * q1.w;
                    acc2 += a.x * q2.x + a.y * q2.y + a.z * q2.z + a.w * q2.w;
                    acc3 += a.x * q3.x + a.y * q3.y + a.z * q3.z + a.w * q3.w;
                }
                __syncthreads();
            }
            if (ks > 0) {
                sh.gm.red[ks - 1][idx][0] = acc0; sh.gm.red[ks - 1][idx][1] = acc1;
                sh.gm.red[ks - 1][idx][2] = acc2; sh.gm.red[ks - 1][idx][3] = acc3;
            }
            __syncthreads();
            if (ks == 0) {
                #pragma unroll
                for (int r = 0; r < 3; ++r) {
                    acc0 += sh.gm.red[r][idx][0]; acc1 += sh.gm.red[r][idx][1];
                    acc2 += sh.gm.red[r][idx][2]; acc3 += sh.gm.red[r][idx][3];
                }
                float cn = sigm(acc1) * c1_reg + sigm(acc0) * tanh_(acc2);
                c1_reg = cn;
                h1n[b * H_ + j] = sigm(acc3) * tanh_(cn);
            }
        }
        grid.sync();

        // ==================== Q ====================
        {
            float acc = 0.0f;
            for (int c = 0; c < 4; ++c) {
                #pragma unroll
                for (int i = 0; i < 8; ++i) {
                    int q   = tid + i * 256;
                    int ksq = q >> 9;
                    int rem = q & 511;
                    int bb  = rem >> 4;
                    int kq  = rem & 15;
                    int kg  = ksq * 256 + c * 64 + kq * 4;
                    *(float4*)&sh.gm.As[ksq][bb][kq * 4] =
                        *(const float4*)(h1n + (size_t)bb * H_ + kg);
                }
                __syncthreads();

                int kbase = ks * 256 + c * 64;
                const float4* w0 = (const float4*)(p.w_in + (size_t)j * H_ + kbase);
                const float4* A4 = (const float4*)&sh.gm.As[ks][b][0];
                #pragma unroll
                for (int kk = 0; kk < 16; ++kk) {
                    float4 a  = A4[kk];
                    float4 q0 = w0[kk];
                    acc += a.x * q0.x + a.y * q0.y + a.z * q0.z + a.w * q0.w;
                }
                __syncthreads();
            }
            if (ks > 0) sh.gm.red[ks - 1][idx][0] = acc;
            __syncthreads();
            if (ks == 0) {
                acc += sh.gm.red[0][idx][0] + sh.gm.red[1][idx][0] + sh.gm.red[2][idx][0];
                p.qbuf[b * H_ + j] = acc;
            }
        }
        grid.sync();

        // ==================== SCORES ====================
        {
            int bs = bid >> 4;
            int st = bid & 15;
            ((float4*)sh.sc.q_lds)[tid] = ((const float4*)(p.qbuf + (size_t)bs * H_))[tid];
            __syncthreads();
            float4 q4[4];
            #pragma unroll
            for (int i = 0; i < 4; ++i) q4[i] = ((const float4*)sh.sc.q_lds)[lane + 64 * i];
            const float* mb = p.mem + (size_t)bs * S_ * H_;
            #pragma unroll
            for (int ss = 0; ss < 4; ++ss) {
                int s = st * 16 + wv * 4 + ss;
                const float4* mr = (const float4*)(mb + (size_t)s * H_);
                float a = 0.0f;
                #pragma unroll
                for (int i = 0; i < 4; ++i) {
                    float4 m = mr[lane + 64 * i];
                    a += q4[i].x * m.x + q4[i].y * m.y + q4[i].z * m.z + q4[i].w * m.w;
                }
                #pragma unroll
                for (int o = 32; o > 0; o >>= 1) a += __shfl_down(a, o);
                if (lane == 0) p.scw[bs * S_ + s] = a;
            }
        }
        grid.sync();

        // ==================== CTX ====================
        {
            int bc = bid >> 4;
            int ht = bid & 15;
            if (wv == 0) {
                int len = p.len[bc];
                float v[4];
                float mx = -1e30f;
                #pragma unroll
                for (int i = 0; i < 4; ++i) {
                    int s = lane + 64 * i;
                    float xv = (s < len) ? p.scw[bc * S_ + s] : -1e9f;
                    v[i] = xv;
                    mx = fmaxf(mx, xv);
                }
                #pragma unroll
                for (int o = 32; o > 0; o >>= 1) mx = fmaxf(mx, __shfl_xor(mx, o));
                float sm = 0.0f;
                #pragma unroll
                for (int i = 0; i < 4; ++i) { v[i] = __expf(v[i] - mx); sm += v[i]; }
                #pragma unroll
                for (int o = 32; o > 0; o >>= 1) sm += __shfl_xor(sm, o);
                float inv = 1.0f / sm;
                #pragma unroll
                for (int i = 0; i < 4; ++i) {
                    int s = lane + 64 * i;
                    float w = v[i] * inv;
                    sh.cx.aw[s] = w;
                    if (ht == 0) p.attn[((size_t)bc * T_ + t) * S_ + s] = w;
                }
            }
            __syncthreads();
            int h = ht * 64 + lane;
            const float* mb = p.mem + (size_t)bc * S_ * H_;
            float a = 0.0f;
            #pragma unroll 8
            for (int ss = 0; ss < 64; ++ss) {
                int s = wv * 64 + ss;
                a += sh.cx.aw[s] * mb[(size_t)s * H_ + h];
            }
            sh.cx.red2[wv][lane] = a;
            __syncthreads();
            if (tid < 64) {
                float r = sh.cx.red2[0][tid] + sh.cx.red2[1][tid] +
                          sh.cx.red2[2][tid] + sh.cx.red2[3][tid];
                p.ctxb[bc * H_ + ht * 64 + tid] = r;
            }
        }
        grid.sync();

        // ==================== OUT ====================
        {
            float acc = 0.0f;
            for (int c = 0; c < 8; ++c) {
                #pragma unroll
                for (int i = 0; i < 8; ++i) {
                    int q   = tid + i * 256;
                    int ksq = q >> 9;
                    int rem = q & 511;
                    int bb  = rem >> 4;
                    int kq  = rem & 15;
                    int kg  = ksq * 512 + c * 64 + kq * 4;
                    const float* src = (kg < 1024) ? (p.ctxb + (size_t)bb * H_ + kg)
                                                   : (h1n + (size_t)bb * H_ + (kg - 1024));
                    *(float4*)&sh.gm.As[ksq][bb][kq * 4] = *(const float4*)src;
                }
                __syncthreads();

                int kbase = ks * 512 + c * 64;
                const float4* w0 = (const float4*)(p.w_out + (size_t)j * 2048 + kbase);
                const float4* A4 = (const float4*)&sh.gm.As[ks][b][0];
                #pragma unroll
                for (int kk = 0; kk < 16; ++kk) {
                    float4 a  = A4[kk];
                    float4 q0 = w0[kk];
                    acc += a.x * q0.x + a.y * q0.y + a.z * q0.z + a.w * q0.w;
                }
                __syncthreads();
            }
            if (ks > 0) sh.gm.red[ks - 1][idx][0] = acc;
            __syncthreads();
            if (ks == 0) {
                acc += sh.gm.red[0][idx][0] + sh.gm.red[1][idx][0] + sh.gm.red[2][idx][0];
                float o = tanh_(acc);
                feedn[b * H_ + j] = o;
                p.dout[((size_t)b * T_ + t) * H_ + j] = o;
            }
        }
        grid.sync();
    }
}

// ===========================================================================
// Fallback path: round-2 multi-kernel pipeline (proven), used only if the
// cooperative launch is rejected.
// ===========================================================================
__global__ void k_init(const float* __restrict__ h0in, const float* __restrict__ c0in,
                       float* h0s, float* c0s, float* h1s, float* c1s, float* feed) {
    int i = blockIdx.x * 256 + threadIdx.x;
    if (i < BH_) {
        h0s[i]  = h0in[i];
        h1s[i]  = h0in[BH_ + i];
        c0s[i]  = c0in[i];
        c1s[i]  = c0in[BH_ + i];
        feed[i] = 0.0f;
    }
}

__global__ __launch_bounds__(256) void k_lstm0(
    const int* __restrict__ tgt, const float* __restrict__ emb,
    const float* __restrict__ w_ih0, const float* __restrict__ w_hh0,
    const float* __restrict__ b_ih0, const float* __restrict__ b_hh0,
    const float* __restrict__ feed, const float* __restrict__ h0c,
    const float* __restrict__ c0c,
    float* __restrict__ h0n, float* __restrict__ c0n, int t)
{
    __shared__ float As[4][32][68];
    __shared__ float red[3][64][4];
    __shared__ int   tok[32];

    int tid = threadIdx.x;
    int b  = tid & 31;
    int jl = (tid >> 5) & 1;
    int ks = tid >> 6;
    int j  = blockIdx.x * 2 + jl;

    if (tid < 32) tok[tid] = tgt[tid * T_ + t];
    __syncthreads();

    float acc0, acc1, acc2, acc3;
    if (ks == 0) {
        acc0 = b_ih0[0 * H_ + j] + b_hh0[0 * H_ + j];
        acc1 = b_ih0[1 * H_ + j] + b_hh0[1 * H_ + j];
        acc2 = b_ih0[2 * H_ + j] + b_hh0[2 * H_ + j];
        acc3 = b_ih0[3 * H_ + j] + b_hh0[3 * H_ + j];
    } else {
        acc0 = acc1 = acc2 = acc3 = 0.0f;
    }

    for (int c = 0; c < 10; ++c) {
        #pragma unroll
        for (int i = 0; i < 8; ++i) {
            int q   = tid + i * 256;
            int ksq = q >> 9;
            int rem = q & 511;
            int bb  = rem >> 4;
            int kq  = rem & 15;
            int kg  = ksq * 640 + c * 64 + kq * 4;
            const float* src;
            if (kg < 512)        src = emb  + (size_t)tok[bb] * E_ + kg;
            else if (kg < 1536)  src = feed + (size_t)bb * H_ + (kg - 512);
            else                 src = h0c  + (size_t)bb * H_ + (kg - 1536);
            *(float4*)&As[ksq][bb][kq * 4] = *(const float4*)src;
        }
        __syncthreads();

        int kbase = ks * 640 + c * 64;
        const float4 *w0, *w1, *w2, *w3;
        if (kbase < 1536) {
            w0 = (const float4*)(w_ih0 + (size_t)(0 * H_ + j) * 1536 + kbase);
            w1 = (const float4*)(w_ih0 + (size_t)(1 * H_ + j) * 1536 + kbase);
            w2 = (const float4*)(w_ih0 + (size_t)(2 * H_ + j) * 1536 + kbase);
            w3 = (const float4*)(w_ih0 + (size_t)(3 * H_ + j) * 1536 + kbase);
        } else {
            int kb = kbase - 1536;
            w0 = (const float4*)(w_hh0 + (size_t)(0 * H_ + j) * 1024 + kb);
            w1 = (const float4*)(w_hh0 + (size_t)(1 * H_ + j) * 1024 + kb);
            w2 = (const float4*)(w_hh0 + (size_t)(2 * H_ + j) * 1024 + kb);
            w3 = (const float4*)(w_hh0 + (size_t)(3 * H_ + j) * 1024 + kb);
        }
        const float4* A4 = (const float4*)&As[ks][b][0];
        #pragma unroll
        for (int kk = 0; kk < 16; ++kk) {
            float4 a  = A4[kk];
            float4 q0 = w0[kk], q1 = w1[kk], q2 = w2[kk], q3 = w3[kk];
            acc0 += a.x * q0.x + a.y * q0.y + a.z * q0.z + a.w * q0.w;
            acc1 += a.x * q1.x + a.y * q1.y + a.z * q1.z + a.w * q1.w;
            acc2 += a.x * q2.x + a.y * q2.y + a.z * q2.z + a.w * q2.w;
            acc3 += a.x * q3.x + a.y * q3.y + a.z * q3.z + a.w * q3.w;
        }
        __syncthreads();
    }

    int idx = tid & 63;
    if (ks > 0) {
        red[ks - 1][idx][0] = acc0; red[ks - 1][idx][1] = acc1;
        red[ks - 1][idx][2] = acc2; red[ks - 1][idx][3] = acc3;
    }
    __syncthreads();
    if (ks == 0) {
        #pragma unroll
        for (int r = 0; r < 3; ++r) {
            acc0 += red[r][idx][0]; acc1 += red[r][idx][1];
            acc2 += red[r][idx][2]; acc3 += red[r][idx][3];
        }
        float co = c0c[b * H_ + j];
        float cn = sigm(acc1) * co + sigm(acc0) * tanh_(acc2);
        float hn = sigm(acc3) * tanh_(cn);
        c0n[b * H_ + j] = cn;
        h0n[b * H_ + j] = hn;
    }
}

__global__ __launch_bounds__(256) void k_lstm1(
    const float* __restrict__ w_ih1, const float* __restrict__ w_hh1,
    const float* __restrict__ b_ih1, const float* __restrict__ b_hh1,
    const float* __restrict__ x, const float* __restrict__ h1c,
    const float* __restrict__ c1c,
    float* __restrict__ h1n, float* __restrict__ c1n)
{
    __shared__ float As[4][32][68];
    __shared__ float red[3][64][4];

    int tid = threadIdx.x;
    int b  = tid & 31;
    int jl = (tid >> 5) & 1;
    int ks = tid >> 6;
    int j  = blockIdx.x * 2 + jl;

    float acc0, acc1, acc2, acc3;
    if (ks == 0) {
        acc0 = b_ih1[0 * H_ + j] + b_hh1[0 * H_ + j];
        acc1 = b_ih1[1 * H_ + j] + b_hh1[1 * H_ + j];
        acc2 = b_ih1[2 * H_ + j] + b_hh1[2 * H_ + j];
        acc3 = b_ih1[3 * H_ + j] + b_hh1[3 * H_ + j];
    } else {
        acc0 = acc1 = acc2 = acc3 = 0.0f;
    }

    for (int c = 0; c < 8; ++c) {
        #pragma unroll
        for (int i = 0; i < 8; ++i) {
            int q   = tid + i * 256;
            int ksq = q >> 9;
            int rem = q & 511;
            int bb  = rem >> 4;
            int kq  = rem & 15;
            int kg  = ksq * 512 + c * 64 + kq * 4;
            const float* src = (kg < 1024) ? (x + (size_t)bb * H_ + kg)
                                           : (h1c + (size_t)bb * H_ + (kg - 1024));
            *(float4*)&As[ksq][bb][kq * 4] = *(const float4*)src;
        }
        __syncthreads();

        int kbase = ks * 512 + c * 64;
        const float* wb;
        int ko;
        if (kbase < 1024) { wb = w_ih1; ko = kbase; }
        else              { wb = w_hh1; ko = kbase - 1024; }
        const float4* w0 = (const float4*)(wb + (size_t)(0 * H_ + j) * H_ + ko);
        const float4* w1 = (const float4*)(wb + (size_t)(1 * H_ + j) * H_ + ko);
        const float4* w2 = (const float4*)(wb + (size_t)(2 * H_ + j) * H_ + ko);
        const float4* w3 = (const float4*)(wb + (size_t)(3 * H_ + j) * H_ + ko);
        const float4* A4 = (const float4*)&As[ks][b][0];
        #pragma unroll
        for (int kk = 0; kk < 16; ++kk) {
            float4 a  = A4[kk];
            float4 q0 = w0[kk], q1 = w1[kk], q2 = w2[kk], q3 = w3[kk];
            acc0 += a.x * q0.x + a.y * q0.y + a.z * q0.z + a.w * q0.w;
            acc1 += a.x * q1.x + a.y * q1.y + a.z * q1.z + a.w * q1.w;
            acc2 += a.x * q2.x + a.y * q2.y + a.z * q2.z + a.w * q2.w;
            acc3 += a.x * q3.x + a.y * q3.y + a.z * q3.z + a.w * q3.w;
        }
        __syncthreads();
    }

    int idx = tid & 63;
    if (ks > 0) {
        red[ks - 1][idx][0] = acc0; red[ks - 1][idx][1] = acc1;
        red[ks - 1][idx][2] = acc2; red[ks - 1][idx][3] = acc3;
    }
    __syncthreads();
    if (ks == 0) {
        #pragma unroll
        for (int r = 0; r < 3; ++r) {
            acc0 += red[r][idx][0]; acc1 += red[r][idx][1];
            acc2 += red[r][idx][2]; acc3 += red[r][idx][3];
        }
        float co = c1c[b * H_ + j];
        float cn = sigm(acc1) * co + sigm(acc0) * tanh_(acc2);
        float hn = sigm(acc3) * tanh_(cn);
        c1n[b * H_ + j] = cn;
        h1n[b * H_ + j] = hn;
    }
}

__global__ __launch_bounds__(256) void k_q(
    const float* __restrict__ w_in, const float* __restrict__ h1n,
    float* __restrict__ q_out)
{
    __shared__ float As[4][32][68];
    __shared__ float red[3][64];

    int tid = threadIdx.x;
    int b  = tid & 31;
    int jl = (tid >> 5) & 1;
    int ks = tid >> 6;
    int j  = blockIdx.x * 2 + jl;

    float acc = 0.0f;
    for (int c = 0; c < 4; ++c) {
        #pragma unroll
        for (int i = 0; i < 8; ++i) {
            int q   = tid + i * 256;
            int ksq = q >> 9;
            int rem = q & 511;
            int bb  = rem >> 4;
            int kq  = rem & 15;
            int kg  = ksq * 256 + c * 64 + kq * 4;
            *(float4*)&As[ksq][bb][kq * 4] = *(const float4*)(h1n + (size_t)bb * H_ + kg);
        }
        __syncthreads();

        int kbase = ks * 256 + c * 64;
        const float4* w0 = (const float4*)(w_in + (size_t)j * H_ + kbase);
        const float4* A4 = (const float4*)&As[ks][b][0];
        #pragma unroll
        for (int kk = 0; kk < 16; ++kk) {
            float4 a  = A4[kk];
            float4 q0 = w0[kk];
            acc += a.x * q0.x + a.y * q0.y + a.z * q0.z + a.w * q0.w;
        }
        __syncthreads();
    }

    int idx = tid & 63;
    if (ks > 0) red[ks - 1][idx] = acc;
    __syncthreads();
    if (ks == 0) {
        acc += red[0][idx] + red[1][idx] + red[2][idx];
        q_out[b * H_ + j] = acc;
    }
}

__global__ __launch_bounds__(256) void k_scores(
    const float* __restrict__ q_in, const float* __restrict__ mem,
    float* __restrict__ sc_out)
{
    __shared__ float q_lds[1024];

    int b  = blockIdx.x >> 4;
    int st = blockIdx.x & 15;
    int tid  = threadIdx.x;
    int lane = tid & 63;
    int wv   = tid >> 6;

    ((float4*)q_lds)[tid] = ((const float4*)(q_in + (size_t)b * H_))[tid];
    __syncthreads();

    float4 q4[4];
    #pragma unroll
    for (int i = 0; i < 4; ++i) q4[i] = ((const float4*)q_lds)[lane + 64 * i];

    const float* mb = mem + (size_t)b * S_ * H_;
    #pragma unroll
    for (int ss = 0; ss < 4; ++ss) {
        int s = st * 16 + wv * 4 + ss;
        const float4* mr = (const float4*)(mb + (size_t)s * H_);
        float a = 0.0f;
        #pragma unroll
        for (int i = 0; i < 4; ++i) {
            float4 m = mr[lane + 64 * i];
            a += q4[i].x * m.x + q4[i].y * m.y + q4[i].z * m.z + q4[i].w * m.w;
        }
        #pragma unroll
        for (int o = 32; o > 0; o >>= 1) a += __shfl_down(a, o);
        if (lane == 0) sc_out[b * S_ + s] = a;
    }
}

__global__ __launch_bounds__(256) void k_ctx(
    const float* __restrict__ sc_in, const float* __restrict__ mem,
    const int* __restrict__ masks,
    float* __restrict__ ctx, float* __restrict__ attn_out, int t)
{
    __shared__ float aw[256];
    __shared__ float red2[4][64];

    int b  = blockIdx.x >> 4;
    int ht = blockIdx.x & 15;
    int tid  = threadIdx.x;
    int lane = tid & 63;
    int wv   = tid >> 6;

    if (wv == 0) {
        int m = 0;
        #pragma unroll
        for (int i = 0; i < 4; ++i) m += masks[b * S_ + lane * 4 + i];
        #pragma unroll
        for (int o = 32; o > 0; o >>= 1) m += __shfl_down(m, o);
        int len = __shfl(m, 0);

        float v[4];
        float mx = -1e30f;
        #pragma unroll
        for (int i = 0; i < 4; ++i) {
            int s = lane + 64 * i;
            float xv = (s < len) ? sc_in[b * S_ + s] : -1e9f;
            v[i] = xv;
            mx = fmaxf(mx, xv);
        }
        #pragma unroll
        for (int o = 32; o > 0; o >>= 1) mx = fmaxf(mx, __shfl_xor(mx, o));
        float sm = 0.0f;
        #pragma unroll
        for (int i = 0; i < 4; ++i) { v[i] = __expf(v[i] - mx); sm += v[i]; }
        #pragma unroll
        for (int o = 32; o > 0; o >>= 1) sm += __shfl_xor(sm, o);
        float inv = 1.0f / sm;
        #pragma unroll
        for (int i = 0; i < 4; ++i) {
            int s = lane + 64 * i;
            float w = v[i] * inv;
            aw[s] = w;
            if (ht == 0) attn_out[((size_t)b * T_ + t) * S_ + s] = w;
        }
    }
    __syncthreads();

    int h = ht * 64 + lane;
    const float* mb = mem + (size_t)b * S_ * H_;
    float a = 0.0f;
    #pragma unroll 8
    for (int ss = 0; ss < 64; ++ss) {
        int s = wv * 64 + ss;
        a += aw[s] * mb[(size_t)s * H_ + h];
    }
    red2[wv][lane] = a;
    __syncthreads();
    if (tid < 64) {
        float r = red2[0][tid] + red2[1][tid] + red2[2][tid] + red2[3][tid];
        ctx[b * H_ + ht * 64 + tid] = r;
    }
}

__global__ __launch_bounds__(256) void k_out(
    const float* __restrict__ w_out, const float* __restrict__ ctx,
    const float* __restrict__ h1n,
    float* __restrict__ feedn, float* __restrict__ dout, int t)
{
    __shared__ float As[4][32][68];
    __shared__ float red[3][64];

    int tid = threadIdx.x;
    int b  = tid & 31;
    int jl = (tid >> 5) & 1;
    int ks = tid >> 6;
    int j  = blockIdx.x * 2 + jl;

    float acc = 0.0f;
    for (int c = 0; c < 8; ++c) {
        #pragma unroll
        for (int i = 0; i < 8; ++i) {
            int q   = tid + i * 256;
            int ksq = q >> 9;
            int rem = q & 511;
            int bb  = rem >> 4;
            int kq  = rem & 15;
            int kg  = ksq * 512 + c * 64 + kq * 4;
            const float* src = (kg < 1024) ? (ctx + (size_t)bb * H_ + kg)
                                           : (h1n + (size_t)bb * H_ + (kg - 1024));
            *(float4*)&As[ksq][bb][kq * 4] = *(const float4*)src;
        }
        __syncthreads();

        int kbase = ks * 512 + c * 64;
        const float4* w0 = (const float4*)(w_out + (size_t)j * 2048 + kbase);
        const float4* A4 = (const float4*)&As[ks][b][0];
        #pragma unroll
        for (int kk = 0; kk < 16; ++kk) {
            float4 a  = A4[kk];
            float4 q0 = w0[kk];
            acc += a.x * q0.x + a.y * q0.y + a.z * q0.z + a.w * q0.w;
        }
        __syncthreads();
    }

    int idx = tid & 63;
    if (ks > 0) red[ks - 1][idx] = acc;
    __syncthreads();
    if (ks == 0) {
        acc += red[0][idx] + red[1][idx] + red[2][idx];
        float o = tanh_(acc);
        feedn[b * H_ + j] = o;
        dout[((size_t)b * T_ + t) * H_ + j] = o;
    }
}

// ---------------------------------------------------------------------------
extern "C" void kernel_launch(void* const* d_in, const int* in_sizes, int n_in,
                              void* d_out, int out_size, void* d_ws, size_t ws_size,
                              hipStream_t stream) {
    Params p;
    p.tgt    = (const int*)  d_in[0];
    p.mem    = (const float*)d_in[1];
    p.masks  = (const int*)  d_in[2];
    p.h0in   = (const float*)d_in[3];
    p.c0in   = (const float*)d_in[4];
    p.emb    = (const float*)d_in[5];
    p.w_ih0  = (const float*)d_in[6];
    p.w_hh0  = (const float*)d_in[7];
    p.b_ih0  = (const float*)d_in[8];
    p.b_hh0  = (const float*)d_in[9];
    p.w_ih1  = (const float*)d_in[10];
    p.w_hh1  = (const float*)d_in[11];
    p.b_ih1  = (const float*)d_in[12];
    p.b_hh1  = (const float*)d_in[13];
    p.w_in   = (const float*)d_in[14];
    p.w_out  = (const float*)d_in[15];

    p.dout = (float*)d_out;
    p.attn = p.dout + (size_t)B_ * T_ * H_;

    float* ws = (float*)d_ws;
    p.h0s  = ws;                       // [2][B*H]
    p.h1s  = ws + 2 * BH_;             // [2][B*H]
    p.feed = ws + 4 * BH_;             // [2][B*H]
    p.qbuf = ws + 6 * BH_;             // [B*H]
    p.ctxb = ws + 7 * BH_;             // [B*H]
    p.scw  = ws + 8 * BH_;             // [B*S]
    p.len  = (int*)(ws + 8 * BH_ + B_ * S_);   // [B]

    void* args[] = { &p };
    hipError_t err = hipLaunchCooperativeKernel(
        reinterpret_cast<void*>(k_decoder), dim3(GRID_), dim3(256), args, 0, stream);

    if (err != hipSuccess) {
        // -------- fallback: round-2 multi-kernel pipeline --------
        float* h0s  = ws;
        float* c0s  = h0s  + 2 * BH_;
        float* h1s  = c0s  + 2 * BH_;
        float* c1s  = h1s  + 2 * BH_;
        float* feed = c1s  + 2 * BH_;
        float* qctx = feed + 2 * BH_;
        float* scw  = qctx + BH_;

        k_init<<<128, 256, 0, stream>>>(p.h0in, p.c0in, h0s, c0s, h1s, c1s, feed);
        for (int t = 0; t < T_; ++t) {
            int cur = t & 1, nxt = cur ^ 1;
            k_lstm0<<<512, 256, 0, stream>>>(p.tgt, p.emb, p.w_ih0, p.w_hh0, p.b_ih0, p.b_hh0,
                                             feed + cur * BH_, h0s + cur * BH_, c0s + cur * BH_,
                                             h0s + nxt * BH_, c0s + nxt * BH_, t);
            k_lstm1<<<512, 256, 0, stream>>>(p.w_ih1, p.w_hh1, p.b_ih1, p.b_hh1,
                                             h0s + nxt * BH_, h1s + cur * BH_, c1s + cur * BH_,
                                             h1s + nxt * BH_, c1s + nxt * BH_);
            k_q<<<512, 256, 0, stream>>>(p.w_in, h1s + nxt * BH_, qctx);
            k_scores<<<512, 256, 0, stream>>>(qctx, p.mem, scw);
            k_ctx<<<512, 256, 0, stream>>>(scw, p.mem, p.masks, qctx, p.attn, t);
            k_out<<<512, 256, 0, stream>>>(p.w_out, qctx, h1s + nxt * BH_,
                                           feed + nxt * BH_, p.dout, t);
        }
    }
}

// Round 4
// 25984.296 us; speedup vs baseline: 1.2089x; 1.2089x over previous
//
#include <hip/hip_runtime.h>
#include <math.h>

#define B_ 32
#define T_ 64
#define S_ 256
#define H_ 1024
#define E_ 512
#define BH_ (B_ * H_)

__device__ __forceinline__ float sigm(float x) {
    return 1.0f / (1.0f + __expf(-x));
}
__device__ __forceinline__ float tanh_(float x) {
    x = fminf(15.0f, fmaxf(-15.0f, x));
    float e = __expf(-2.0f * x);
    return (1.0f - e) / (1.0f + e);
}
// f32 -> bf16 round-to-nearest-even (finite inputs)
__device__ __forceinline__ unsigned short f2bf(float f) {
    unsigned int u = __float_as_uint(f);
    u = (u + 0x7fffu + ((u >> 16) & 1u)) >> 16;
    return (unsigned short)u;
}
// unpack one uint holding 2 bf16 (lo = even k, hi = odd k)
__device__ __forceinline__ float bflo(unsigned int u) { return __uint_as_float(u << 16); }
__device__ __forceinline__ float bfhi(unsigned int u) { return __uint_as_float(u & 0xffff0000u); }

// ---------------------------------------------------------------------------
// init: state ping-pong slot 0 + zero input feed
// ---------------------------------------------------------------------------
__global__ void k_init(const float* __restrict__ h0in, const float* __restrict__ c0in,
                       float* h0s, float* c0s, float* h1s, float* c1s, float* feed) {
    int i = blockIdx.x * 256 + threadIdx.x;
    if (i < BH_) {
        h0s[i]  = h0in[i];
        h1s[i]  = h0in[BH_ + i];
        c0s[i]  = c0in[i];
        c1s[i]  = c0in[BH_ + i];
        feed[i] = 0.0f;
    }
}

// ---------------------------------------------------------------------------
// weight f32 -> bf16 (RNE), concatenating [ih | hh] per row.  grid = rows.
// For single-matrix conversion pass Kb = 0 (and bsrc = a).
// ---------------------------------------------------------------------------
__global__ __launch_bounds__(256) void k_cvt2(
    const float* __restrict__ a, const float* __restrict__ bsrc,
    unsigned short* __restrict__ dst, int Ka, int Kb)
{
    int r = blockIdx.x;
    int K = Ka + Kb;
    const float* ra = a + (size_t)r * Ka;
    const float* rb = bsrc + (size_t)r * Kb;
    unsigned short* d = dst + (size_t)r * K;
    for (int k4 = threadIdx.x * 4; k4 < K; k4 += 1024) {
        float4 v = (k4 < Ka) ? *(const float4*)(ra + k4)
                             : *(const float4*)(rb + (k4 - Ka));
        ushort4 u;
        u.x = f2bf(v.x); u.y = f2bf(v.y); u.z = f2bf(v.z); u.w = f2bf(v.w);
        *(ushort4*)(d + k4) = u;
    }
}

// ===========================================================================
// bf16-weight GEMM kernels.  block 512 = 32 b x 2 jl x 8 ks, grid 512.
// A (activations) staged per 64-k chunk in f32 LDS, shared by both jl.
// Weights packed bf16 [G*1024 rows][K], read 16B (8 elems) per instr.
// ===========================================================================

// -------- LSTM layer 0: K = 2560 = [emb 512 | feed 1024 | h0 1024] ---------
__global__ __launch_bounds__(512, 4) void k_lstm0b(
    const int* __restrict__ tgt, const float* __restrict__ emb,
    const unsigned short* __restrict__ wb,
    const float* __restrict__ b_ih, const float* __restrict__ b_hh,
    const float* __restrict__ feed, const float* __restrict__ h0c,
    const float* __restrict__ c0c,
    float* __restrict__ h0n, float* __restrict__ c0n, int t)
{
    __shared__ float As[8][32][68];      // 69.6 KB, +4 pad
    __shared__ int   tok[32];

    const int tid = threadIdx.x;
    const int b  = tid & 31;
    const int jl = (tid >> 5) & 1;
    const int ks = tid >> 6;
    const int j  = blockIdx.x * 2 + jl;

    if (tid < 32) tok[tid] = tgt[tid * T_ + t];
    __syncthreads();

    float acc0 = 0.f, acc1 = 0.f, acc2 = 0.f, acc3 = 0.f;
    const unsigned short* w0 = wb + (size_t)(0 * H_ + j) * 2560;
    const unsigned short* w1 = wb + (size_t)(1 * H_ + j) * 2560;
    const unsigned short* w2 = wb + (size_t)(2 * H_ + j) * 2560;
    const unsigned short* w3 = wb + (size_t)(3 * H_ + j) * 2560;

    for (int c = 0; c < 5; ++c) {
        #pragma unroll
        for (int i = 0; i < 8; ++i) {
            int s   = tid + i * 512;
            int kss = s >> 9;
            int rem = s & 511;
            int bb  = rem >> 4;
            int kq  = rem & 15;
            int kg  = kss * 320 + c * 64 + kq * 4;
            const float* src;
            if (kg < 512)        src = emb  + (size_t)tok[bb] * E_ + kg;
            else if (kg < 1536)  src = feed + (size_t)bb * H_ + (kg - 512);
            else                 src = h0c  + (size_t)bb * H_ + (kg - 1536);
            *(float4*)&As[kss][bb][kq * 4] = *(const float4*)src;
        }
        __syncthreads();

        const int k0 = ks * 320 + c * 64;
        const float4* A4 = (const float4*)&As[ks][b][0];
        #pragma unroll
        for (int kk = 0; kk < 8; ++kk) {
            float4 alo = A4[kk * 2];
            float4 ahi = A4[kk * 2 + 1];
            uint4 wv;
            wv = *(const uint4*)(w0 + k0 + kk * 8);
            acc0 += alo.x*bflo(wv.x)+alo.y*bfhi(wv.x)+alo.z*bflo(wv.y)+alo.w*bfhi(wv.y)
                  + ahi.x*bflo(wv.z)+ahi.y*bfhi(wv.z)+ahi.z*bflo(wv.w)+ahi.w*bfhi(wv.w);
            wv = *(const uint4*)(w1 + k0 + kk * 8);
            acc1 += alo.x*bflo(wv.x)+alo.y*bfhi(wv.x)+alo.z*bflo(wv.y)+alo.w*bfhi(wv.y)
                  + ahi.x*bflo(wv.z)+ahi.y*bfhi(wv.z)+ahi.z*bflo(wv.w)+ahi.w*bfhi(wv.w);
            wv = *(const uint4*)(w2 + k0 + kk * 8);
            acc2 += alo.x*bflo(wv.x)+alo.y*bfhi(wv.x)+alo.z*bflo(wv.y)+alo.w*bfhi(wv.y)
                  + ahi.x*bflo(wv.z)+ahi.y*bfhi(wv.z)+ahi.z*bflo(wv.w)+ahi.w*bfhi(wv.w);
            wv = *(const uint4*)(w3 + k0 + kk * 8);
            acc3 += alo.x*bflo(wv.x)+alo.y*bfhi(wv.x)+alo.z*bflo(wv.y)+alo.w*bfhi(wv.y)
                  + ahi.x*bflo(wv.z)+ahi.y*bfhi(wv.z)+ahi.z*bflo(wv.w)+ahi.w*bfhi(wv.w);
        }
        __syncthreads();
    }

    float* redp = (float*)&As[0][0][0];   // As dead now; alias for reduction
    if (ks > 0) {
        int base = (((ks - 1) * 2 + jl) * 32 + b) * 4;
        redp[base+0] = acc0; redp[base+1] = acc1;
        redp[base+2] = acc2; redp[base+3] = acc3;
    }
    __syncthreads();
    if (ks == 0) {
        #pragma unroll
        for (int r = 0; r < 7; ++r) {
            int base = ((r * 2 + jl) * 32 + b) * 4;
            acc0 += redp[base+0]; acc1 += redp[base+1];
            acc2 += redp[base+2]; acc3 += redp[base+3];
        }
        acc0 += b_ih[0*H_+j] + b_hh[0*H_+j];
        acc1 += b_ih[1*H_+j] + b_hh[1*H_+j];
        acc2 += b_ih[2*H_+j] + b_hh[2*H_+j];
        acc3 += b_ih[3*H_+j] + b_hh[3*H_+j];
        float co = c0c[b * H_ + j];
        float cn = sigm(acc1) * co + sigm(acc0) * tanh_(acc2);
        c0n[b * H_ + j] = cn;
        h0n[b * H_ + j] = sigm(acc3) * tanh_(cn);
    }
}

// -------- LSTM layer 1: K = 2048 = [h0n 1024 | h1 1024] --------------------
__global__ __launch_bounds__(512, 4) void k_lstm1b(
    const unsigned short* __restrict__ wb,
    const float* __restrict__ b_ih, const float* __restrict__ b_hh,
    const float* __restrict__ x, const float* __restrict__ h1c,
    const float* __restrict__ c1c,
    float* __restrict__ h1n, float* __restrict__ c1n)
{
    __shared__ float As[8][32][68];

    const int tid = threadIdx.x;
    const int b  = tid & 31;
    const int jl = (tid >> 5) & 1;
    const int ks = tid >> 6;
    const int j  = blockIdx.x * 2 + jl;

    float acc0 = 0.f, acc1 = 0.f, acc2 = 0.f, acc3 = 0.f;
    const unsigned short* w0 = wb + (size_t)(0 * H_ + j) * 2048;
    const unsigned short* w1 = wb + (size_t)(1 * H_ + j) * 2048;
    const unsigned short* w2 = wb + (size_t)(2 * H_ + j) * 2048;
    const unsigned short* w3 = wb + (size_t)(3 * H_ + j) * 2048;

    for (int c = 0; c < 4; ++c) {
        #pragma unroll
        for (int i = 0; i < 8; ++i) {
            int s   = tid + i * 512;
            int kss = s >> 9;
            int rem = s & 511;
            int bb  = rem >> 4;
            int kq  = rem & 15;
            int kg  = kss * 256 + c * 64 + kq * 4;
            const float* src = (kg < 1024) ? (x + (size_t)bb * H_ + kg)
                                           : (h1c + (size_t)bb * H_ + (kg - 1024));
            *(float4*)&As[kss][bb][kq * 4] = *(const float4*)src;
        }
        __syncthreads();

        const int k0 = ks * 256 + c * 64;
        const float4* A4 = (const float4*)&As[ks][b][0];
        #pragma unroll
        for (int kk = 0; kk < 8; ++kk) {
            float4 alo = A4[kk * 2];
            float4 ahi = A4[kk * 2 + 1];
            uint4 wv;
            wv = *(const uint4*)(w0 + k0 + kk * 8);
            acc0 += alo.x*bflo(wv.x)+alo.y*bfhi(wv.x)+alo.z*bflo(wv.y)+alo.w*bfhi(wv.y)
                  + ahi.x*bflo(wv.z)+ahi.y*bfhi(wv.z)+ahi.z*bflo(wv.w)+ahi.w*bfhi(wv.w);
            wv = *(const uint4*)(w1 + k0 + kk * 8);
            acc1 += alo.x*bflo(wv.x)+alo.y*bfhi(wv.x)+alo.z*bflo(wv.y)+alo.w*bfhi(wv.y)
                  + ahi.x*bflo(wv.z)+ahi.y*bfhi(wv.z)+ahi.z*bflo(wv.w)+ahi.w*bfhi(wv.w);
            wv = *(const uint4*)(w2 + k0 + kk * 8);
            acc2 += alo.x*bflo(wv.x)+alo.y*bfhi(wv.x)+alo.z*bflo(wv.y)+alo.w*bfhi(wv.y)
                  + ahi.x*bflo(wv.z)+ahi.y*bfhi(wv.z)+ahi.z*bflo(wv.w)+ahi.w*bfhi(wv.w);
            wv = *(const uint4*)(w3 + k0 + kk * 8);
            acc3 += alo.x*bflo(wv.x)+alo.y*bfhi(wv.x)+alo.z*bflo(wv.y)+alo.w*bfhi(wv.y)
                  + ahi.x*bflo(wv.z)+ahi.y*bfhi(wv.z)+ahi.z*bflo(wv.w)+ahi.w*bfhi(wv.w);
        }
        __syncthreads();
    }

    float* redp = (float*)&As[0][0][0];
    if (ks > 0) {
        int base = (((ks - 1) * 2 + jl) * 32 + b) * 4;
        redp[base+0] = acc0; redp[base+1] = acc1;
        redp[base+2] = acc2; redp[base+3] = acc3;
    }
    __syncthreads();
    if (ks == 0) {
        #pragma unroll
        for (int r = 0; r < 7; ++r) {
            int base = ((r * 2 + jl) * 32 + b) * 4;
            acc0 += redp[base+0]; acc1 += redp[base+1];
            acc2 += redp[base+2]; acc3 += redp[base+3];
        }
        acc0 += b_ih[0*H_+j] + b_hh[0*H_+j];
        acc1 += b_ih[1*H_+j] + b_hh[1*H_+j];
        acc2 += b_ih[2*H_+j] + b_hh[2*H_+j];
        acc3 += b_ih[3*H_+j] + b_hh[3*H_+j];
        float co = c1c[b * H_ + j];
        float cn = sigm(acc1) * co + sigm(acc0) * tanh_(acc2);
        c1n[b * H_ + j] = cn;
        h1n[b * H_ + j] = sigm(acc3) * tanh_(cn);
    }
}

// -------- q = h1n @ w_in^T : K = 1024, G = 1 -------------------------------
__global__ __launch_bounds__(512, 4) void k_qb(
    const unsigned short* __restrict__ wb, const float* __restrict__ h1n,
    float* __restrict__ q_out)
{
    __shared__ float As[8][32][68];

    const int tid = threadIdx.x;
    const int b  = tid & 31;
    const int jl = (tid >> 5) & 1;
    const int ks = tid >> 6;
    const int j  = blockIdx.x * 2 + jl;

    float acc = 0.f;
    const unsigned short* w0 = wb + (size_t)j * 1024;

    for (int c = 0; c < 2; ++c) {
        #pragma unroll
        for (int i = 0; i < 8; ++i) {
            int s   = tid + i * 512;
            int kss = s >> 9;
            int rem = s & 511;
            int bb  = rem >> 4;
            int kq  = rem & 15;
            int kg  = kss * 128 + c * 64 + kq * 4;
            *(float4*)&As[kss][bb][kq * 4] = *(const float4*)(h1n + (size_t)bb * H_ + kg);
        }
        __syncthreads();

        const int k0 = ks * 128 + c * 64;
        const float4* A4 = (const float4*)&As[ks][b][0];
        #pragma unroll
        for (int kk = 0; kk < 8; ++kk) {
            float4 alo = A4[kk * 2];
            float4 ahi = A4[kk * 2 + 1];
            uint4 wv = *(const uint4*)(w0 + k0 + kk * 8);
            acc += alo.x*bflo(wv.x)+alo.y*bfhi(wv.x)+alo.z*bflo(wv.y)+alo.w*bfhi(wv.y)
                 + ahi.x*bflo(wv.z)+ahi.y*bfhi(wv.z)+ahi.z*bflo(wv.w)+ahi.w*bfhi(wv.w);
        }
        __syncthreads();
    }

    float* redp = (float*)&As[0][0][0];
    if (ks > 0) redp[((ks - 1) * 2 + jl) * 32 + b] = acc;
    __syncthreads();
    if (ks == 0) {
        #pragma unroll
        for (int r = 0; r < 7; ++r) acc += redp[(r * 2 + jl) * 32 + b];
        q_out[b * H_ + j] = acc;
    }
}

// -------- out = tanh([ctx | h1n] @ w_out^T) : K = 2048, G = 1 --------------
__global__ __launch_bounds__(512, 4) void k_outb(
    const unsigned short* __restrict__ wb, const float* __restrict__ ctx,
    const float* __restrict__ h1n,
    float* __restrict__ feedn, float* __restrict__ dout, int t)
{
    __shared__ float As[8][32][68];

    const int tid = threadIdx.x;
    const int b  = tid & 31;
    const int jl = (tid >> 5) & 1;
    const int ks = tid >> 6;
    const int j  = blockIdx.x * 2 + jl;

    float acc = 0.f;
    const unsigned short* w0 = wb + (size_t)j * 2048;

    for (int c = 0; c < 4; ++c) {
        #pragma unroll
        for (int i = 0; i < 8; ++i) {
            int s   = tid + i * 512;
            int kss = s >> 9;
            int rem = s & 511;
            int bb  = rem >> 4;
            int kq  = rem & 15;
            int kg  = kss * 256 + c * 64 + kq * 4;
            const float* src = (kg < 1024) ? (ctx + (size_t)bb * H_ + kg)
                                           : (h1n + (size_t)bb * H_ + (kg - 1024));
            *(float4*)&As[kss][bb][kq * 4] = *(const float4*)src;
        }
        __syncthreads();

        const int k0 = ks * 256 + c * 64;
        const float4* A4 = (const float4*)&As[ks][b][0];
        #pragma unroll
        for (int kk = 0; kk < 8; ++kk) {
            float4 alo = A4[kk * 2];
            float4 ahi = A4[kk * 2 + 1];
            uint4 wv = *(const uint4*)(w0 + k0 + kk * 8);
            acc += alo.x*bflo(wv.x)+alo.y*bfhi(wv.x)+alo.z*bflo(wv.y)+alo.w*bfhi(wv.y)
                 + ahi.x*bflo(wv.z)+ahi.y*bfhi(wv.z)+ahi.z*bflo(wv.w)+ahi.w*bfhi(wv.w);
        }
        __syncthreads();
    }

    float* redp = (float*)&As[0][0][0];
    if (ks > 0) redp[((ks - 1) * 2 + jl) * 32 + b] = acc;
    __syncthreads();
    if (ks == 0) {
        #pragma unroll
        for (int r = 0; r < 7; ++r) acc += redp[(r * 2 + jl) * 32 + b];
        float o = tanh_(acc);
        feedn[b * H_ + j] = o;
        dout[((size_t)b * T_ + t) * H_ + j] = o;
    }
}

// ---------------------------------------------------------------------------
// scores[b][s] = q[b] . mem[b][s]   grid 512 = b(32) x stile(16), block 256
// ---------------------------------------------------------------------------
__global__ __launch_bounds__(256) void k_scores(
    const float* __restrict__ q_in, const float* __restrict__ mem,
    float* __restrict__ sc_out)
{
    __shared__ float q_lds[1024];

    int b  = blockIdx.x >> 4;
    int st = blockIdx.x & 15;
    int tid  = threadIdx.x;
    int lane = tid & 63;
    int wv   = tid >> 6;

    ((float4*)q_lds)[tid] = ((const float4*)(q_in + (size_t)b * H_))[tid];
    __syncthreads();

    float4 q4[4];
    #pragma unroll
    for (int i = 0; i < 4; ++i) q4[i] = ((const float4*)q_lds)[lane + 64 * i];

    const float* mb = mem + (size_t)b * S_ * H_;
    #pragma unroll
    for (int ss = 0; ss < 4; ++ss) {
        int s = st * 16 + wv * 4 + ss;
        const float4* mr = (const float4*)(mb + (size_t)s * H_);
        float a = 0.0f;
        #pragma unroll
        for (int i = 0; i < 4; ++i) {
            float4 m = mr[lane + 64 * i];
            a += q4[i].x * m.x + q4[i].y * m.y + q4[i].z * m.z + q4[i].w * m.w;
        }
        #pragma unroll
        for (int o = 32; o > 0; o >>= 1) a += __shfl_down(a, o);
        if (lane == 0) sc_out[b * S_ + s] = a;
    }
}

// ---------------------------------------------------------------------------
// ctx: local masked softmax of scores + weighted sum.  grid 512, block 256
// ---------------------------------------------------------------------------
__global__ __launch_bounds__(256) void k_ctx(
    const float* __restrict__ sc_in, const float* __restrict__ mem,
    const int* __restrict__ masks,
    float* __restrict__ ctx, float* __restrict__ attn_out, int t)
{
    __shared__ float aw[256];
    __shared__ float red2[4][64];

    int b  = blockIdx.x >> 4;
    int ht = blockIdx.x & 15;
    int tid  = threadIdx.x;
    int lane = tid & 63;
    int wv   = tid >> 6;

    if (wv == 0) {
        int m = 0;
        #pragma unroll
        for (int i = 0; i < 4; ++i) m += masks[b * S_ + lane * 4 + i];
        #pragma unroll
        for (int o = 32; o > 0; o >>= 1) m += __shfl_down(m, o);
        int len = __shfl(m, 0);

        float v[4];
        float mx = -1e30f;
        #pragma unroll
        for (int i = 0; i < 4; ++i) {
            int s = lane + 64 * i;
            float xv = (s < len) ? sc_in[b * S_ + s] : -1e9f;
            v[i] = xv;
            mx = fmaxf(mx, xv);
        }
        #pragma unroll
        for (int o = 32; o > 0; o >>= 1) mx = fmaxf(mx, __shfl_xor(mx, o));
        float sm = 0.0f;
        #pragma unroll
        for (int i = 0; i < 4; ++i) { v[i] = __expf(v[i] - mx); sm += v[i]; }
        #pragma unroll
        for (int o = 32; o > 0; o >>= 1) sm += __shfl_xor(sm, o);
        float inv = 1.0f / sm;
        #pragma unroll
        for (int i = 0; i < 4; ++i) {
            int s = lane + 64 * i;
            float w = v[i] * inv;
            aw[s] = w;
            if (ht == 0) attn_out[((size_t)b * T_ + t) * S_ + s] = w;
        }
    }
    __syncthreads();

    int h = ht * 64 + lane;
    const float* mb = mem + (size_t)b * S_ * H_;
    float a = 0.0f;
    #pragma unroll 8
    for (int ss = 0; ss < 64; ++ss) {
        int s = wv * 64 + ss;
        a += aw[s] * mb[(size_t)s * H_ + h];
    }
    red2[wv][lane] = a;
    __syncthreads();
    if (tid < 64) {
        float r = red2[0][tid] + red2[1][tid] + red2[2][tid] + red2[3][tid];
        ctx[b * H_ + ht * 64 + tid] = r;
    }
}

// ===========================================================================
// f32 fallback GEMM kernels (round-2, proven) — used only if ws too small
// ===========================================================================
__global__ __launch_bounds__(256) void k_lstm0(
    const int* __restrict__ tgt, const float* __restrict__ emb,
    const float* __restrict__ w_ih0, const float* __restrict__ w_hh0,
    const float* __restrict__ b_ih0, const float* __restrict__ b_hh0,
    const float* __restrict__ feed, const float* __restrict__ h0c,
    const float* __restrict__ c0c,
    float* __restrict__ h0n, float* __restrict__ c0n, int t)
{
    __shared__ float As[4][32][68];
    __shared__ float red[3][64][4];
    __shared__ int   tok[32];

    int tid = threadIdx.x;
    int b  = tid & 31;
    int jl = (tid >> 5) & 1;
    int ks = tid >> 6;
    int j  = blockIdx.x * 2 + jl;

    if (tid < 32) tok[tid] = tgt[tid * T_ + t];
    __syncthreads();

    float acc0, acc1, acc2, acc3;
    if (ks == 0) {
        acc0 = b_ih0[0 * H_ + j] + b_hh0[0 * H_ + j];
        acc1 = b_ih0[1 * H_ + j] + b_hh0[1 * H_ + j];
        acc2 = b_ih0[2 * H_ + j] + b_hh0[2 * H_ + j];
        acc3 = b_ih0[3 * H_ + j] + b_hh0[3 * H_ + j];
    } else {
        acc0 = acc1 = acc2 = acc3 = 0.0f;
    }

    for (int c = 0; c < 10; ++c) {
        #pragma unroll
        for (int i = 0; i < 8; ++i) {
            int q   = tid + i * 256;
            int ksq = q >> 9;
            int rem = q & 511;
            int bb  = rem >> 4;
            int kq  = rem & 15;
            int kg  = ksq * 640 + c * 64 + kq * 4;
            const float* src;
            if (kg < 512)        src = emb  + (size_t)tok[bb] * E_ + kg;
            else if (kg < 1536)  src = feed + (size_t)bb * H_ + (kg - 512);
            else                 src = h0c  + (size_t)bb * H_ + (kg - 1536);
            *(float4*)&As[ksq][bb][kq * 4] = *(const float4*)src;
        }
        __syncthreads();

        int kbase = ks * 640 + c * 64;
        const float4 *w0, *w1, *w2, *w3;
        if (kbase < 1536) {
            w0 = (const float4*)(w_ih0 + (size_t)(0 * H_ + j) * 1536 + kbase);
            w1 = (const float4*)(w_ih0 + (size_t)(1 * H_ + j) * 1536 + kbase);
            w2 = (const float4*)(w_ih0 + (size_t)(2 * H_ + j) * 1536 + kbase);
            w3 = (const float4*)(w_ih0 + (size_t)(3 * H_ + j) * 1536 + kbase);
        } else {
            int kb = kbase - 1536;
            w0 = (const float4*)(w_hh0 + (size_t)(0 * H_ + j) * 1024 + kb);
            w1 = (const float4*)(w_hh0 + (size_t)(1 * H_ + j) * 1024 + kb);
            w2 = (const float4*)(w_hh0 + (size_t)(2 * H_ + j) * 1024 + kb);
            w3 = (const float4*)(w_hh0 + (size_t)(3 * H_ + j) * 1024 + kb);
        }
        const float4* A4 = (const float4*)&As[ks][b][0];
        #pragma unroll
        for (int kk = 0; kk < 16; ++kk) {
            float4 a  = A4[kk];
            float4 q0 = w0[kk], q1 = w1[kk], q2 = w2[kk], q3 = w3[kk];
            acc0 += a.x * q0.x + a.y * q0.y + a.z * q0.z + a.w * q0.w;
            acc1 += a.x * q1.x + a.y * q1.y + a.z * q1.z + a.w * q1.w;
            acc2 += a.x * q2.x + a.y * q2.y + a.z * q2.z + a.w * q2.w;
            acc3 += a.x * q3.x + a.y * q3.y + a.z * q3.z + a.w * q3.w;
        }
        __syncthreads();
    }

    int idx = tid & 63;
    if (ks > 0) {
        red[ks - 1][idx][0] = acc0; red[ks - 1][idx][1] = acc1;
        red[ks - 1][idx][2] = acc2; red[ks - 1][idx][3] = acc3;
    }
    __syncthreads();
    if (ks == 0) {
        #pragma unroll
        for (int r = 0; r < 3; ++r) {
            acc0 += red[r][idx][0]; acc1 += red[r][idx][1];
            acc2 += red[r][idx][2]; acc3 += red[r][idx][3];
        }
        float co = c0c[b * H_ + j];
        float cn = sigm(acc1) * co + sigm(acc0) * tanh_(acc2);
        float hn = sigm(acc3) * tanh_(cn);
        c0n[b * H_ + j] = cn;
        h0n[b * H_ + j] = hn;
    }
}

__global__ __launch_bounds__(256) void k_lstm1(
    const float* __restrict__ w_ih1, const float* __restrict__ w_hh1,
    const float* __restrict__ b_ih1, const float* __restrict__ b_hh1,
    const float* __restrict__ x, const float* __restrict__ h1c,
    const float* __restrict__ c1c,
    float* __restrict__ h1n, float* __restrict__ c1n)
{
    __shared__ float As[4][32][68];
    __shared__ float red[3][64][4];

    int tid = threadIdx.x;
    int b  = tid & 31;
    int jl = (tid >> 5) & 1;
    int ks = tid >> 6;
    int j  = blockIdx.x * 2 + jl;

    float acc0, acc1, acc2, acc3;
    if (ks == 0) {
        acc0 = b_ih1[0 * H_ + j] + b_hh1[0 * H_ + j];
        acc1 = b_ih1[1 * H_ + j] + b_hh1[1 * H_ + j];
        acc2 = b_ih1[2 * H_ + j] + b_hh1[2 * H_ + j];
        acc3 = b_ih1[3 * H_ + j] + b_hh1[3 * H_ + j];
    } else {
        acc0 = acc1 = acc2 = acc3 = 0.0f;
    }

    for (int c = 0; c < 8; ++c) {
        #pragma unroll
        for (int i = 0; i < 8; ++i) {
            int q   = tid + i * 256;
            int ksq = q >> 9;
            int rem = q & 511;
            int bb  = rem >> 4;
            int kq  = rem & 15;
            int kg  = ksq * 512 + c * 64 + kq * 4;
            const float* src = (kg < 1024) ? (x + (size_t)bb * H_ + kg)
                                           : (h1c + (size_t)bb * H_ + (kg - 1024));
            *(float4*)&As[ksq][bb][kq * 4] = *(const float4*)src;
        }
        __syncthreads();

        int kbase = ks * 512 + c * 64;
        const float* wb;
        int ko;
        if (kbase < 1024) { wb = w_ih1; ko = kbase; }
        else              { wb = w_hh1; ko = kbase - 1024; }
        const float4* w0 = (const float4*)(wb + (size_t)(0 * H_ + j) * H_ + ko);
        const float4* w1 = (const float4*)(wb + (size_t)(1 * H_ + j) * H_ + ko);
        const float4* w2 = (const float4*)(wb + (size_t)(2 * H_ + j) * H_ + ko);
        const float4* w3 = (const float4*)(wb + (size_t)(3 * H_ + j) * H_ + ko);
        const float4* A4 = (const float4*)&As[ks][b][0];
        #pragma unroll
        for (int kk = 0; kk < 16; ++kk) {
            float4 a  = A4[kk];
            float4 q0 = w0[kk], q1 = w1[kk], q2 = w2[kk], q3 = w3[kk];
            acc0 += a.x * q0.x + a.y * q0.y + a.z * q0.z + a.w * q0.w;
            acc1 += a.x * q1.x + a.y * q1.y + a.z * q1.z + a.w * q1.w;
            acc2 += a.x * q2.x + a.y * q2.y + a.z * q2.z + a.w * q2.w;
            acc3 += a.x * q3.x + a.y * q3.y + a.z * q3.z + a.w * q3.w;
        }
        __syncthreads();
    }

    int idx = tid & 63;
    if (ks > 0) {
        red[ks - 1][idx][0] = acc0; red[ks - 1][idx][1] = acc1;
        red[ks - 1][idx][2] = acc2; red[ks - 1][idx][3] = acc3;
    }
    __syncthreads();
    if (ks == 0) {
        #pragma unroll
        for (int r = 0; r < 3; ++r) {
            acc0 += red[r][idx][0]; acc1 += red[r][idx][1];
            acc2 += red[r][idx][2]; acc3 += red[r][idx][3];
        }
        float co = c1c[b * H_ + j];
        float cn = sigm(acc1) * co + sigm(acc0) * tanh_(acc2);
        float hn = sigm(acc3) * tanh_(cn);
        c1n[b * H_ + j] = cn;
        h1n[b * H_ + j] = hn;
    }
}

__global__ __launch_bounds__(256) void k_q(
    const float* __restrict__ w_in, const float* __restrict__ h1n,
    float* __restrict__ q_out)
{
    __shared__ float As[4][32][68];
    __shared__ float red[3][64];

    int tid = threadIdx.x;
    int b  = tid & 31;
    int jl = (tid >> 5) & 1;
    int ks = tid >> 6;
    int j  = blockIdx.x * 2 + jl;

    float acc = 0.0f;
    for (int c = 0; c < 4; ++c) {
        #pragma unroll
        for (int i = 0; i < 8; ++i) {
            int q   = tid + i * 256;
            int ksq = q >> 9;
            int rem = q & 511;
            int bb  = rem >> 4;
            int kq  = rem & 15;
            int kg  = ksq * 256 + c * 64 + kq * 4;
            *(float4*)&As[ksq][bb][kq * 4] = *(const float4*)(h1n + (size_t)bb * H_ + kg);
        }
        __syncthreads();

        int kbase = ks * 256 + c * 64;
        const float4* w0 = (const float4*)(w_in + (size_t)j * H_ + kbase);
        const float4* A4 = (const float4*)&As[ks][b][0];
        #pragma unroll
        for (int kk = 0; kk < 16; ++kk) {
            float4 a  = A4[kk];
            float4 q0 = w0[kk];
            acc += a.x * q0.x + a.y * q0.y + a.z * q0.z + a.w * q0.w;
        }
        __syncthreads();
    }

    int idx = tid & 63;
    if (ks > 0) red[ks - 1][idx] = acc;
    __syncthreads();
    if (ks == 0) {
        acc += red[0][idx] + red[1][idx] + red[2][idx];
        q_out[b * H_ + j] = acc;
    }
}

__global__ __launch_bounds__(256) void k_out(
    const float* __restrict__ w_out, const float* __restrict__ ctx,
    const float* __restrict__ h1n,
    float* __restrict__ feedn, float* __restrict__ dout, int t)
{
    __shared__ float As[4][32][68];
    __shared__ float red[3][64];

    int tid = threadIdx.x;
    int b  = tid & 31;
    int jl = (tid >> 5) & 1;
    int ks = tid >> 6;
    int j  = blockIdx.x * 2 + jl;

    float acc = 0.0f;
    for (int c = 0; c < 8; ++c) {
        #pragma unroll
        for (int i = 0; i < 8; ++i) {
            int q   = tid + i * 256;
            int ksq = q >> 9;
            int rem = q & 511;
            int bb  = rem >> 4;
            int kq  = rem & 15;
            int kg  = ksq * 512 + c * 64 + kq * 4;
            const float* src = (kg < 1024) ? (ctx + (size_t)bb * H_ + kg)
                                           : (h1n + (size_t)bb * H_ + (kg - 1024));
            *(float4*)&As[ksq][bb][kq * 4] = *(const float4*)src;
        }
        __syncthreads();

        int kbase = ks * 512 + c * 64;
        const float4* w0 = (const float4*)(w_out + (size_t)j * 2048 + kbase);
        const float4* A4 = (const float4*)&As[ks][b][0];
        #pragma unroll
        for (int kk = 0; kk < 16; ++kk) {
            float4 a  = A4[kk];
            float4 q0 = w0[kk];
            acc += a.x * q0.x + a.y * q0.y + a.z * q0.z + a.w * q0.w;
        }
        __syncthreads();
    }

    int idx = tid & 63;
    if (ks > 0) red[ks - 1][idx] = acc;
    __syncthreads();
    if (ks == 0) {
        acc += red[0][idx] + red[1][idx] + red[2][idx];
        float o = tanh_(acc);
        feedn[b * H_ + j] = o;
        dout[((size_t)b * T_ + t) * H_ + j] = o;
    }
}

// ---------------------------------------------------------------------------
extern "C" void kernel_launch(void* const* d_in, const int* in_sizes, int n_in,
                              void* d_out, int out_size, void* d_ws, size_t ws_size,
                              hipStream_t stream) {
    const int*   tgt    = (const int*)  d_in[0];
    const float* mem    = (const float*)d_in[1];
    const int*   masks  = (const int*)  d_in[2];
    const float* h0in   = (const float*)d_in[3];
    const float* c0in   = (const float*)d_in[4];
    const float* emb    = (const float*)d_in[5];
    const float* w_ih0  = (const float*)d_in[6];
    const float* w_hh0  = (const float*)d_in[7];
    const float* b_ih0  = (const float*)d_in[8];
    const float* b_hh0  = (const float*)d_in[9];
    const float* w_ih1  = (const float*)d_in[10];
    const float* w_hh1  = (const float*)d_in[11];
    const float* b_ih1  = (const float*)d_in[12];
    const float* b_hh1  = (const float*)d_in[13];
    const float* w_in   = (const float*)d_in[14];
    const float* w_out  = (const float*)d_in[15];

    float* dout     = (float*)d_out;
    float* attn_out = dout + (size_t)B_ * T_ * H_;

    // ---- bf16 workspace layout ----
    const size_t nwb0 = (size_t)4096 * 2560;   // lstm0 packed weights (bf16)
    const size_t nwb1 = (size_t)4096 * 2048;   // lstm1
    const size_t nwq  = (size_t)1024 * 1024;   // w_in
    const size_t nwo  = (size_t)1024 * 2048;   // w_out
    const size_t wbytes = (nwb0 + nwb1 + nwq + nwo) * sizeof(unsigned short);
    const size_t fbytes = (size_t)(2+2+2+2+2) * BH_ * 4 + (size_t)2 * BH_ * 4
                        + (size_t)B_ * S_ * 4 + 256;   // states+qbuf+ctxb+scw+len
    const bool use_bf16 = (ws_size >= wbytes + fbytes);

    if (use_bf16) {
        unsigned short* wb0 = (unsigned short*)d_ws;
        unsigned short* wb1 = wb0 + nwb0;
        unsigned short* wq  = wb1 + nwb1;
        unsigned short* wo  = wq  + nwq;
        float* fs   = (float*)(wo + nwo);
        float* h0s  = fs;                  // [2][B*H]
        float* h1s  = h0s + 2 * BH_;
        float* c0s  = h1s + 2 * BH_;
        float* c1s  = c0s + 2 * BH_;
        float* feed = c1s + 2 * BH_;
        float* qbuf = feed + 2 * BH_;      // [B*H]
        float* ctxb = qbuf + BH_;          // [B*H]
        float* scw  = ctxb + BH_;          // [B*S]

        // per-call weight conversion (graph-deterministic)
        k_cvt2<<<4096, 256, 0, stream>>>(w_ih0, w_hh0, wb0, 1536, 1024);
        k_cvt2<<<4096, 256, 0, stream>>>(w_ih1, w_hh1, wb1, 1024, 1024);
        k_cvt2<<<1024, 256, 0, stream>>>(w_in,  w_in,  wq,  1024, 0);
        k_cvt2<<<1024, 256, 0, stream>>>(w_out, w_out, wo,  2048, 0);
        k_init<<<128, 256, 0, stream>>>(h0in, c0in, h0s, c0s, h1s, c1s, feed);

        for (int t = 0; t < T_; ++t) {
            int cur = t & 1, nxt = cur ^ 1;
            k_lstm0b<<<512, 512, 0, stream>>>(tgt, emb, wb0, b_ih0, b_hh0,
                                              feed + cur * BH_, h0s + cur * BH_, c0s + cur * BH_,
                                              h0s + nxt * BH_, c0s + nxt * BH_, t);
            k_lstm1b<<<512, 512, 0, stream>>>(wb1, b_ih1, b_hh1,
                                              h0s + nxt * BH_, h1s + cur * BH_, c1s + cur * BH_,
                                              h1s + nxt * BH_, c1s + nxt * BH_);
            k_qb<<<512, 512, 0, stream>>>(wq, h1s + nxt * BH_, qbuf);
            k_scores<<<512, 256, 0, stream>>>(qbuf, mem, scw);
            k_ctx<<<512, 256, 0, stream>>>(scw, mem, masks, ctxb, attn_out, t);
            k_outb<<<512, 512, 0, stream>>>(wo, ctxb, h1s + nxt * BH_,
                                            feed + nxt * BH_, dout, t);
        }
    } else {
        // -------- f32 fallback (round-2 pipeline) --------
        float* ws   = (float*)d_ws;
        float* h0s  = ws;
        float* c0s  = h0s  + 2 * BH_;
        float* h1s  = c0s  + 2 * BH_;
        float* c1s  = h1s  + 2 * BH_;
        float* feed = c1s  + 2 * BH_;
        float* qctx = feed + 2 * BH_;
        float* scw  = qctx + BH_;

        k_init<<<128, 256, 0, stream>>>(h0in, c0in, h0s, c0s, h1s, c1s, feed);
        for (int t = 0; t < T_; ++t) {
            int cur = t & 1, nxt = cur ^ 1;
            k_lstm0<<<512, 256, 0, stream>>>(tgt, emb, w_ih0, w_hh0, b_ih0, b_hh0,
                                             feed + cur * BH_, h0s + cur * BH_, c0s + cur * BH_,
                                             h0s + nxt * BH_, c0s + nxt * BH_, t);
            k_lstm1<<<512, 256, 0, stream>>>(w_ih1, w_hh1, b_ih1, b_hh1,
                                             h0s + nxt * BH_, h1s + cur * BH_, c1s + cur * BH_,
                                             h1s + nxt * BH_, c1s + nxt * BH_);
            k_q<<<512, 256, 0, stream>>>(w_in, h1s + nxt * BH_, qctx);
            k_scores<<<512, 256, 0, stream>>>(qctx, mem, scw);
            k_ctx<<<512, 256, 0, stream>>>(scw, mem, masks, qctx, attn_out, t);
            k_out<<<512, 256, 0, stream>>>(w_out, qctx, h1s + nxt * BH_,
                                           feed + nxt * BH_, dout, t);
        }
    }
}

// Round 5
// 25589.455 us; speedup vs baseline: 1.2275x; 1.0154x over previous
//
#include <hip/hip_runtime.h>
#include <math.h>

#define B_ 32
#define T_ 64
#define S_ 256
#define H_ 1024
#define E_ 512
#define BH_ (B_ * H_)

__device__ __forceinline__ float sigm(float x) {
    return 1.0f / (1.0f + __expf(-x));
}
__device__ __forceinline__ float tanh_(float x) {
    x = fminf(15.0f, fmaxf(-15.0f, x));
    float e = __expf(-2.0f * x);
    return (1.0f - e) / (1.0f + e);
}
// f32 -> bf16 round-to-nearest-even (finite inputs)
__device__ __forceinline__ unsigned short f2bf(float f) {
    unsigned int u = __float_as_uint(f);
    u = (u + 0x7fffu + ((u >> 16) & 1u)) >> 16;
    return (unsigned short)u;
}
// unpack one uint holding 2 bf16 (lo = even k, hi = odd k)
__device__ __forceinline__ float bflo(unsigned int u) { return __uint_as_float(u << 16); }
__device__ __forceinline__ float bfhi(unsigned int u) { return __uint_as_float(u & 0xffff0000u); }

// ---------------------------------------------------------------------------
// init: state ping-pong slot 0 + zero input feed
// ---------------------------------------------------------------------------
__global__ void k_init(const float* __restrict__ h0in, const float* __restrict__ c0in,
                       float* h0s, float* c0s, float* h1s, float* c1s, float* feed) {
    int i = blockIdx.x * 256 + threadIdx.x;
    if (i < BH_) {
        h0s[i]  = h0in[i];
        h1s[i]  = h0in[BH_ + i];
        c0s[i]  = c0in[i];
        c1s[i]  = c0in[BH_ + i];
        feed[i] = 0.0f;
    }
}

// ---------------------------------------------------------------------------
// weight f32 -> bf16 (RNE), concatenating [ih | hh] per row.  grid = rows.
// For single-matrix conversion pass Kb = 0 (and bsrc = a).
// ---------------------------------------------------------------------------
__global__ __launch_bounds__(256) void k_cvt2(
    const float* __restrict__ a, const float* __restrict__ bsrc,
    unsigned short* __restrict__ dst, int Ka, int Kb)
{
    int r = blockIdx.x;
    int K = Ka + Kb;
    const float* ra = a + (size_t)r * Ka;
    const float* rb = bsrc + (size_t)r * Kb;
    unsigned short* d = dst + (size_t)r * K;
    for (int k4 = threadIdx.x * 4; k4 < K; k4 += 1024) {
        float4 v = (k4 < Ka) ? *(const float4*)(ra + k4)
                             : *(const float4*)(rb + (k4 - Ka));
        ushort4 u;
        u.x = f2bf(v.x); u.y = f2bf(v.y); u.z = f2bf(v.z); u.w = f2bf(v.w);
        *(ushort4*)(d + k4) = u;
    }
}

// ===========================================================================
// bf16-weight GEMM kernels.  block 512 = 32 b x 2 jl x 8 ks, grid 512.
// A (activations) staged per 64-k chunk in f32 LDS, shared by both jl.
// Weights packed bf16 [G*1024 rows][K], read 16B (8 elems) per instr.
// ===========================================================================

// -------- LSTM layer 0: K = 2560 = [emb 512 | feed 1024 | h0 1024] ---------
__global__ __launch_bounds__(512, 4) void k_lstm0b(
    const int* __restrict__ tgt, const float* __restrict__ emb,
    const unsigned short* __restrict__ wb,
    const float* __restrict__ b_ih, const float* __restrict__ b_hh,
    const float* __restrict__ feed, const float* __restrict__ h0c,
    const float* __restrict__ c0c,
    float* __restrict__ h0n, float* __restrict__ c0n, int t)
{
    __shared__ float As[8][32][68];      // 69.6 KB, +4 pad
    __shared__ int   tok[32];

    const int tid = threadIdx.x;
    const int b  = tid & 31;
    const int jl = (tid >> 5) & 1;
    const int ks = tid >> 6;
    const int j  = blockIdx.x * 2 + jl;

    if (tid < 32) tok[tid] = tgt[tid * T_ + t];
    __syncthreads();

    float acc0 = 0.f, acc1 = 0.f, acc2 = 0.f, acc3 = 0.f;
    const unsigned short* w0 = wb + (size_t)(0 * H_ + j) * 2560;
    const unsigned short* w1 = wb + (size_t)(1 * H_ + j) * 2560;
    const unsigned short* w2 = wb + (size_t)(2 * H_ + j) * 2560;
    const unsigned short* w3 = wb + (size_t)(3 * H_ + j) * 2560;

    for (int c = 0; c < 5; ++c) {
        #pragma unroll
        for (int i = 0; i < 8; ++i) {
            int s   = tid + i * 512;
            int kss = s >> 9;
            int rem = s & 511;
            int bb  = rem >> 4;
            int kq  = rem & 15;
            int kg  = kss * 320 + c * 64 + kq * 4;
            const float* src;
            if (kg < 512)        src = emb  + (size_t)tok[bb] * E_ + kg;
            else if (kg < 1536)  src = feed + (size_t)bb * H_ + (kg - 512);
            else                 src = h0c  + (size_t)bb * H_ + (kg - 1536);
            *(float4*)&As[kss][bb][kq * 4] = *(const float4*)src;
        }
        __syncthreads();

        const int k0 = ks * 320 + c * 64;
        const float4* A4 = (const float4*)&As[ks][b][0];
        #pragma unroll
        for (int kk = 0; kk < 8; ++kk) {
            float4 alo = A4[kk * 2];
            float4 ahi = A4[kk * 2 + 1];
            uint4 wv;
            wv = *(const uint4*)(w0 + k0 + kk * 8);
            acc0 += alo.x*bflo(wv.x)+alo.y*bfhi(wv.x)+alo.z*bflo(wv.y)+alo.w*bfhi(wv.y)
                  + ahi.x*bflo(wv.z)+ahi.y*bfhi(wv.z)+ahi.z*bflo(wv.w)+ahi.w*bfhi(wv.w);
            wv = *(const uint4*)(w1 + k0 + kk * 8);
            acc1 += alo.x*bflo(wv.x)+alo.y*bfhi(wv.x)+alo.z*bflo(wv.y)+alo.w*bfhi(wv.y)
                  + ahi.x*bflo(wv.z)+ahi.y*bfhi(wv.z)+ahi.z*bflo(wv.w)+ahi.w*bfhi(wv.w);
            wv = *(const uint4*)(w2 + k0 + kk * 8);
            acc2 += alo.x*bflo(wv.x)+alo.y*bfhi(wv.x)+alo.z*bflo(wv.y)+alo.w*bfhi(wv.y)
                  + ahi.x*bflo(wv.z)+ahi.y*bfhi(wv.z)+ahi.z*bflo(wv.w)+ahi.w*bfhi(wv.w);
            wv = *(const uint4*)(w3 + k0 + kk * 8);
            acc3 += alo.x*bflo(wv.x)+alo.y*bfhi(wv.x)+alo.z*bflo(wv.y)+alo.w*bfhi(wv.y)
                  + ahi.x*bflo(wv.z)+ahi.y*bfhi(wv.z)+ahi.z*bflo(wv.w)+ahi.w*bfhi(wv.w);
        }
        __syncthreads();
    }

    float* redp = (float*)&As[0][0][0];   // As dead now; alias for reduction
    if (ks > 0) {
        int base = (((ks - 1) * 2 + jl) * 32 + b) * 4;
        redp[base+0] = acc0; redp[base+1] = acc1;
        redp[base+2] = acc2; redp[base+3] = acc3;
    }
    __syncthreads();
    if (ks == 0) {
        #pragma unroll
        for (int r = 0; r < 7; ++r) {
            int base = ((r * 2 + jl) * 32 + b) * 4;
            acc0 += redp[base+0]; acc1 += redp[base+1];
            acc2 += redp[base+2]; acc3 += redp[base+3];
        }
        acc0 += b_ih[0*H_+j] + b_hh[0*H_+j];
        acc1 += b_ih[1*H_+j] + b_hh[1*H_+j];
        acc2 += b_ih[2*H_+j] + b_hh[2*H_+j];
        acc3 += b_ih[3*H_+j] + b_hh[3*H_+j];
        float co = c0c[b * H_ + j];
        float cn = sigm(acc1) * co + sigm(acc0) * tanh_(acc2);
        c0n[b * H_ + j] = cn;
        h0n[b * H_ + j] = sigm(acc3) * tanh_(cn);
    }
}

// -------- LSTM layer 1: K = 2048 = [h0n 1024 | h1 1024] --------------------
__global__ __launch_bounds__(512, 4) void k_lstm1b(
    const unsigned short* __restrict__ wb,
    const float* __restrict__ b_ih, const float* __restrict__ b_hh,
    const float* __restrict__ x, const float* __restrict__ h1c,
    const float* __restrict__ c1c,
    float* __restrict__ h1n, float* __restrict__ c1n)
{
    __shared__ float As[8][32][68];

    const int tid = threadIdx.x;
    const int b  = tid & 31;
    const int jl = (tid >> 5) & 1;
    const int ks = tid >> 6;
    const int j  = blockIdx.x * 2 + jl;

    float acc0 = 0.f, acc1 = 0.f, acc2 = 0.f, acc3 = 0.f;
    const unsigned short* w0 = wb + (size_t)(0 * H_ + j) * 2048;
    const unsigned short* w1 = wb + (size_t)(1 * H_ + j) * 2048;
    const unsigned short* w2 = wb + (size_t)(2 * H_ + j) * 2048;
    const unsigned short* w3 = wb + (size_t)(3 * H_ + j) * 2048;

    for (int c = 0; c < 4; ++c) {
        #pragma unroll
        for (int i = 0; i < 8; ++i) {
            int s   = tid + i * 512;
            int kss = s >> 9;
            int rem = s & 511;
            int bb  = rem >> 4;
            int kq  = rem & 15;
            int kg  = kss * 256 + c * 64 + kq * 4;
            const float* src = (kg < 1024) ? (x + (size_t)bb * H_ + kg)
                                           : (h1c + (size_t)bb * H_ + (kg - 1024));
            *(float4*)&As[kss][bb][kq * 4] = *(const float4*)src;
        }
        __syncthreads();

        const int k0 = ks * 256 + c * 64;
        const float4* A4 = (const float4*)&As[ks][b][0];
        #pragma unroll
        for (int kk = 0; kk < 8; ++kk) {
            float4 alo = A4[kk * 2];
            float4 ahi = A4[kk * 2 + 1];
            uint4 wv;
            wv = *(const uint4*)(w0 + k0 + kk * 8);
            acc0 += alo.x*bflo(wv.x)+alo.y*bfhi(wv.x)+alo.z*bflo(wv.y)+alo.w*bfhi(wv.y)
                  + ahi.x*bflo(wv.z)+ahi.y*bfhi(wv.z)+ahi.z*bflo(wv.w)+ahi.w*bfhi(wv.w);
            wv = *(const uint4*)(w1 + k0 + kk * 8);
            acc1 += alo.x*bflo(wv.x)+alo.y*bfhi(wv.x)+alo.z*bflo(wv.y)+alo.w*bfhi(wv.y)
                  + ahi.x*bflo(wv.z)+ahi.y*bfhi(wv.z)+ahi.z*bflo(wv.w)+ahi.w*bfhi(wv.w);
            wv = *(const uint4*)(w2 + k0 + kk * 8);
            acc2 += alo.x*bflo(wv.x)+alo.y*bfhi(wv.x)+alo.z*bflo(wv.y)+alo.w*bfhi(wv.y)
                  + ahi.x*bflo(wv.z)+ahi.y*bfhi(wv.z)+ahi.z*bflo(wv.w)+ahi.w*bfhi(wv.w);
            wv = *(const uint4*)(w3 + k0 + kk * 8);
            acc3 += alo.x*bflo(wv.x)+alo.y*bfhi(wv.x)+alo.z*bflo(wv.y)+alo.w*bfhi(wv.y)
                  + ahi.x*bflo(wv.z)+ahi.y*bfhi(wv.z)+ahi.z*bflo(wv.w)+ahi.w*bfhi(wv.w);
        }
        __syncthreads();
    }

    float* redp = (float*)&As[0][0][0];
    if (ks > 0) {
        int base = (((ks - 1) * 2 + jl) * 32 + b) * 4;
        redp[base+0] = acc0; redp[base+1] = acc1;
        redp[base+2] = acc2; redp[base+3] = acc3;
    }
    __syncthreads();
    if (ks == 0) {
        #pragma unroll
        for (int r = 0; r < 7; ++r) {
            int base = ((r * 2 + jl) * 32 + b) * 4;
            acc0 += redp[base+0]; acc1 += redp[base+1];
            acc2 += redp[base+2]; acc3 += redp[base+3];
        }
        acc0 += b_ih[0*H_+j] + b_hh[0*H_+j];
        acc1 += b_ih[1*H_+j] + b_hh[1*H_+j];
        acc2 += b_ih[2*H_+j] + b_hh[2*H_+j];
        acc3 += b_ih[3*H_+j] + b_hh[3*H_+j];
        float co = c1c[b * H_ + j];
        float cn = sigm(acc1) * co + sigm(acc0) * tanh_(acc2);
        c1n[b * H_ + j] = cn;
        h1n[b * H_ + j] = sigm(acc3) * tanh_(cn);
    }
}

// -------- q = h1n @ w_in^T : K = 1024, G = 1 -------------------------------
__global__ __launch_bounds__(512, 4) void k_qb(
    const unsigned short* __restrict__ wb, const float* __restrict__ h1n,
    float* __restrict__ q_out)
{
    __shared__ float As[8][32][68];

    const int tid = threadIdx.x;
    const int b  = tid & 31;
    const int jl = (tid >> 5) & 1;
    const int ks = tid >> 6;
    const int j  = blockIdx.x * 2 + jl;

    float acc = 0.f;
    const unsigned short* w0 = wb + (size_t)j * 1024;

    for (int c = 0; c < 2; ++c) {
        #pragma unroll
        for (int i = 0; i < 8; ++i) {
            int s   = tid + i * 512;
            int kss = s >> 9;
            int rem = s & 511;
            int bb  = rem >> 4;
            int kq  = rem & 15;
            int kg  = kss * 128 + c * 64 + kq * 4;
            *(float4*)&As[kss][bb][kq * 4] = *(const float4*)(h1n + (size_t)bb * H_ + kg);
        }
        __syncthreads();

        const int k0 = ks * 128 + c * 64;
        const float4* A4 = (const float4*)&As[ks][b][0];
        #pragma unroll
        for (int kk = 0; kk < 8; ++kk) {
            float4 alo = A4[kk * 2];
            float4 ahi = A4[kk * 2 + 1];
            uint4 wv = *(const uint4*)(w0 + k0 + kk * 8);
            acc += alo.x*bflo(wv.x)+alo.y*bfhi(wv.x)+alo.z*bflo(wv.y)+alo.w*bfhi(wv.y)
                 + ahi.x*bflo(wv.z)+ahi.y*bfhi(wv.z)+ahi.z*bflo(wv.w)+ahi.w*bfhi(wv.w);
        }
        __syncthreads();
    }

    float* redp = (float*)&As[0][0][0];
    if (ks > 0) redp[((ks - 1) * 2 + jl) * 32 + b] = acc;
    __syncthreads();
    if (ks == 0) {
        #pragma unroll
        for (int r = 0; r < 7; ++r) acc += redp[(r * 2 + jl) * 32 + b];
        q_out[b * H_ + j] = acc;
    }
}

// -------- out = tanh([ctx | h1n] @ w_out^T) : K = 2048, G = 1 --------------
__global__ __launch_bounds__(512, 4) void k_outb(
    const unsigned short* __restrict__ wb, const float* __restrict__ ctx,
    const float* __restrict__ h1n,
    float* __restrict__ feedn, float* __restrict__ dout, int t)
{
    __shared__ float As[8][32][68];

    const int tid = threadIdx.x;
    const int b  = tid & 31;
    const int jl = (tid >> 5) & 1;
    const int ks = tid >> 6;
    const int j  = blockIdx.x * 2 + jl;

    float acc = 0.f;
    const unsigned short* w0 = wb + (size_t)j * 2048;

    for (int c = 0; c < 4; ++c) {
        #pragma unroll
        for (int i = 0; i < 8; ++i) {
            int s   = tid + i * 512;
            int kss = s >> 9;
            int rem = s & 511;
            int bb  = rem >> 4;
            int kq  = rem & 15;
            int kg  = kss * 256 + c * 64 + kq * 4;
            const float* src = (kg < 1024) ? (ctx + (size_t)bb * H_ + kg)
                                           : (h1n + (size_t)bb * H_ + (kg - 1024));
            *(float4*)&As[kss][bb][kq * 4] = *(const float4*)src;
        }
        __syncthreads();

        const int k0 = ks * 256 + c * 64;
        const float4* A4 = (const float4*)&As[ks][b][0];
        #pragma unroll
        for (int kk = 0; kk < 8; ++kk) {
            float4 alo = A4[kk * 2];
            float4 ahi = A4[kk * 2 + 1];
            uint4 wv = *(const uint4*)(w0 + k0 + kk * 8);
            acc += alo.x*bflo(wv.x)+alo.y*bfhi(wv.x)+alo.z*bflo(wv.y)+alo.w*bfhi(wv.y)
                 + ahi.x*bflo(wv.z)+ahi.y*bfhi(wv.z)+ahi.z*bflo(wv.w)+ahi.w*bfhi(wv.w);
        }
        __syncthreads();
    }

    float* redp = (float*)&As[0][0][0];
    if (ks > 0) redp[((ks - 1) * 2 + jl) * 32 + b] = acc;
    __syncthreads();
    if (ks == 0) {
        #pragma unroll
        for (int r = 0; r < 7; ++r) acc += redp[(r * 2 + jl) * 32 + b];
        float o = tanh_(acc);
        feedn[b * H_ + j] = o;
        dout[((size_t)b * T_ + t) * H_ + j] = o;
    }
}

// ---------------------------------------------------------------------------
// scores[b][s] = q[b] . mem[b][s]   grid 512 = b(32) x stile(16), block 256
// ---------------------------------------------------------------------------
__global__ __launch_bounds__(256) void k_scores(
    const float* __restrict__ q_in, const float* __restrict__ mem,
    float* __restrict__ sc_out)
{
    __shared__ float q_lds[1024];

    int b  = blockIdx.x >> 4;
    int st = blockIdx.x & 15;
    int tid  = threadIdx.x;
    int lane = tid & 63;
    int wv   = tid >> 6;

    ((float4*)q_lds)[tid] = ((const float4*)(q_in + (size_t)b * H_))[tid];
    __syncthreads();

    float4 q4[4];
    #pragma unroll
    for (int i = 0; i < 4; ++i) q4[i] = ((const float4*)q_lds)[lane + 64 * i];

    const float* mb = mem + (size_t)b * S_ * H_;
    #pragma unroll
    for (int ss = 0; ss < 4; ++ss) {
        int s = st * 16 + wv * 4 + ss;
        const float4* mr = (const float4*)(mb + (size_t)s * H_);
        float a = 0.0f;
        #pragma unroll
        for (int i = 0; i < 4; ++i) {
            float4 m = mr[lane + 64 * i];
            a += q4[i].x * m.x + q4[i].y * m.y + q4[i].z * m.z + q4[i].w * m.w;
        }
        #pragma unroll
        for (int o = 32; o > 0; o >>= 1) a += __shfl_down(a, o);
        if (lane == 0) sc_out[b * S_ + s] = a;
    }
}

// ---------------------------------------------------------------------------
// ctx: local masked softmax of scores + weighted sum.  grid 512, block 256
// ---------------------------------------------------------------------------
__global__ __launch_bounds__(256) void k_ctx(
    const float* __restrict__ sc_in, const float* __restrict__ mem,
    const int* __restrict__ masks,
    float* __restrict__ ctx, float* __restrict__ attn_out, int t)
{
    __shared__ float aw[256];
    __shared__ float red2[4][64];

    int b  = blockIdx.x >> 4;
    int ht = blockIdx.x & 15;
    int tid  = threadIdx.x;
    int lane = tid & 63;
    int wv   = tid >> 6;

    if (wv == 0) {
        int m = 0;
        #pragma unroll
        for (int i = 0; i < 4; ++i) m += masks[b * S_ + lane * 4 + i];
        #pragma unroll
        for (int o = 32; o > 0; o >>= 1) m += __shfl_down(m, o);
        int len = __shfl(m, 0);

        float v[4];
        float mx = -1e30f;
        #pragma unroll
        for (int i = 0; i < 4; ++i) {
            int s = lane + 64 * i;
            float xv = (s < len) ? sc_in[b * S_ + s] : -1e9f;
            v[i] = xv;
            mx = fmaxf(mx, xv);
        }
        #pragma unroll
        for (int o = 32; o > 0; o >>= 1) mx = fmaxf(mx, __shfl_xor(mx, o));
        float sm = 0.0f;
        #pragma unroll
        for (int i = 0; i < 4; ++i) { v[i] = __expf(v[i] - mx); sm += v[i]; }
        #pragma unroll
        for (int o = 32; o > 0; o >>= 1) sm += __shfl_xor(sm, o);
        float inv = 1.0f / sm;
        #pragma unroll
        for (int i = 0; i < 4; ++i) {
            int s = lane + 64 * i;
            float w = v[i] * inv;
            aw[s] = w;
            if (ht == 0) attn_out[((size_t)b * T_ + t) * S_ + s] = w;
        }
    }
    __syncthreads();

    int h = ht * 64 + lane;
    const float* mb = mem + (size_t)b * S_ * H_;
    float a = 0.0f;
    #pragma unroll 8
    for (int ss = 0; ss < 64; ++ss) {
        int s = wv * 64 + ss;
        a += aw[s] * mb[(size_t)s * H_ + h];
    }
    red2[wv][lane] = a;
    __syncthreads();
    if (tid < 64) {
        float r = red2[0][tid] + red2[1][tid] + red2[2][tid] + red2[3][tid];
        ctx[b * H_ + ht * 64 + tid] = r;
    }
}

// ===========================================================================
// f32 fallback GEMM kernels (round-2, proven) — used only if ws too small
// ===========================================================================
__global__ __launch_bounds__(256) void k_lstm0(
    const int* __restrict__ tgt, const float* __restrict__ emb,
    const float* __restrict__ w_ih0, const float* __restrict__ w_hh0,
    const float* __restrict__ b_ih0, const float* __restrict__ b_hh0,
    const float* __restrict__ feed, const float* __restrict__ h0c,
    const float* __restrict__ c0c,
    float* __restrict__ h0n, float* __restrict__ c0n, int t)
{
    __shared__ float As[4][32][68];
    __shared__ float red[3][64][4];
    __shared__ int   tok[32];

    int tid = threadIdx.x;
    int b  = tid & 31;
    int jl = (tid >> 5) & 1;
    int ks = tid >> 6;
    int j  = blockIdx.x * 2 + jl;

    if (tid < 32) tok[tid] = tgt[tid * T_ + t];
    __syncthreads();

    float acc0, acc1, acc2, acc3;
    if (ks == 0) {
        acc0 = b_ih0[0 * H_ + j] + b_hh0[0 * H_ + j];
        acc1 = b_ih0[1 * H_ + j] + b_hh0[1 * H_ + j];
        acc2 = b_ih0[2 * H_ + j] + b_hh0[2 * H_ + j];
        acc3 = b_ih0[3 * H_ + j] + b_hh0[3 * H_ + j];
    } else {
        acc0 = acc1 = acc2 = acc3 = 0.0f;
    }

    for (int c = 0; c < 10; ++c) {
        #pragma unroll
        for (int i = 0; i < 8; ++i) {
            int q   = tid + i * 256;
            int ksq = q >> 9;
            int rem = q & 511;
            int bb  = rem >> 4;
            int kq  = rem & 15;
            int kg  = ksq * 640 + c * 64 + kq * 4;
            const float* src;
            if (kg < 512)        src = emb  + (size_t)tok[bb] * E_ + kg;
            else if (kg < 1536)  src = feed + (size_t)bb * H_ + (kg - 512);
            else                 src = h0c  + (size_t)bb * H_ + (kg - 1536);
            *(float4*)&As[ksq][bb][kq * 4] = *(const float4*)src;
        }
        __syncthreads();

        int kbase = ks * 640 + c * 64;
        const float4 *w0, *w1, *w2, *w3;
        if (kbase < 1536) {
            w0 = (const float4*)(w_ih0 + (size_t)(0 * H_ + j) * 1536 + kbase);
            w1 = (const float4*)(w_ih0 + (size_t)(1 * H_ + j) * 1536 + kbase);
            w2 = (const float4*)(w_ih0 + (size_t)(2 * H_ + j) * 1536 + kbase);
            w3 = (const float4*)(w_ih0 + (size_t)(3 * H_ + j) * 1536 + kbase);
        } else {
            int kb = kbase - 1536;
            w0 = (const float4*)(w_hh0 + (size_t)(0 * H_ + j) * 1024 + kb);
            w1 = (const float4*)(w_hh0 + (size_t)(1 * H_ + j) * 1024 + kb);
            w2 = (const float4*)(w_hh0 + (size_t)(2 * H_ + j) * 1024 + kb);
            w3 = (const float4*)(w_hh0 + (size_t)(3 * H_ + j) * 1024 + kb);
        }
        const float4* A4 = (const float4*)&As[ks][b][0];
        #pragma unroll
        for (int kk = 0; kk < 16; ++kk) {
            float4 a  = A4[kk];
            float4 q0 = w0[kk], q1 = w1[kk], q2 = w2[kk], q3 = w3[kk];
            acc0 += a.x * q0.x + a.y * q0.y + a.z * q0.z + a.w * q0.w;
            acc1 += a.x * q1.x + a.y * q1.y + a.z * q1.z + a.w * q1.w;
            acc2 += a.x * q2.x + a.y * q2.y + a.z * q2.z + a.w * q2.w;
            acc3 += a.x * q3.x + a.y * q3.y + a.z * q3.z + a.w * q3.w;
        }
        __syncthreads();
    }

    int idx = tid & 63;
    if (ks > 0) {
        red[ks - 1][idx][0] = acc0; red[ks - 1][idx][1] = acc1;
        red[ks - 1][idx][2] = acc2; red[ks - 1][idx][3] = acc3;
    }
    __syncthreads();
    if (ks == 0) {
        #pragma unroll
        for (int r = 0; r < 3; ++r) {
            acc0 += red[r][idx][0]; acc1 += red[r][idx][1];
            acc2 += red[r][idx][2]; acc3 += red[r][idx][3];
        }
        float co = c0c[b * H_ + j];
        float cn = sigm(acc1) * co + sigm(acc0) * tanh_(acc2);
        float hn = sigm(acc3) * tanh_(cn);
        c0n[b * H_ + j] = cn;
        h0n[b * H_ + j] = hn;
    }
}

__global__ __launch_bounds__(256) void k_lstm1(
    const float* __restrict__ w_ih1, const float* __restrict__ w_hh1,
    const float* __restrict__ b_ih1, const float* __restrict__ b_hh1,
    const float* __restrict__ x, const float* __restrict__ h1c,
    const float* __restrict__ c1c,
    float* __restrict__ h1n, float* __restrict__ c1n)
{
    __shared__ float As[4][32][68];
    __shared__ float red[3][64][4];

    int tid = threadIdx.x;
    int b  = tid & 31;
    int jl = (tid >> 5) & 1;
    int ks = tid >> 6;
    int j  = blockIdx.x * 2 + jl;

    float acc0, acc1, acc2, acc3;
    if (ks == 0) {
        acc0 = b_ih1[0 * H_ + j] + b_hh1[0 * H_ + j];
        acc1 = b_ih1[1 * H_ + j] + b_hh1[1 * H_ + j];
        acc2 = b_ih1[2 * H_ + j] + b_hh1[2 * H_ + j];
        acc3 = b_ih1[3 * H_ + j] + b_hh1[3 * H_ + j];
    } else {
        acc0 = acc1 = acc2 = acc3 = 0.0f;
    }

    for (int c = 0; c < 8; ++c) {
        #pragma unroll
        for (int i = 0; i < 8; ++i) {
            int q   = tid + i * 256;
            int ksq = q >> 9;
            int rem = q & 511;
            int bb  = rem >> 4;
            int kq  = rem & 15;
            int kg  = ksq * 512 + c * 64 + kq * 4;
            const float* src = (kg < 1024) ? (x + (size_t)bb * H_ + kg)
                                           : (h1c + (size_t)bb * H_ + (kg - 1024));
            *(float4*)&As[ksq][bb][kq * 4] = *(const float4*)src;
        }
        __syncthreads();

        int kbase = ks * 512 + c * 64;
        const float* wb;
        int ko;
        if (kbase < 1024) { wb = w_ih1; ko = kbase; }
        else              { wb = w_hh1; ko = kbase - 1024; }
        const float4* w0 = (const float4*)(wb + (size_t)(0 * H_ + j) * H_ + ko);
        const float4* w1 = (const float4*)(wb + (size_t)(1 * H_ + j) * H_ + ko);
        const float4* w2 = (const float4*)(wb + (size_t)(2 * H_ + j) * H_ + ko);
        const float4* w3 = (const float4*)(wb + (size_t)(3 * H_ + j) * H_ + ko);
        const float4* A4 = (const float4*)&As[ks][b][0];
        #pragma unroll
        for (int kk = 0; kk < 16; ++kk) {
            float4 a  = A4[kk];
            float4 q0 = w0[kk], q1 = w1[kk], q2 = w2[kk], q3 = w3[kk];
            acc0 += a.x * q0.x + a.y * q0.y + a.z * q0.z + a.w * q0.w;
            acc1 += a.x * q1.x + a.y * q1.y + a.z * q1.z + a.w * q1.w;
            acc2 += a.x * q2.x + a.y * q2.y + a.z * q2.z + a.w * q2.w;
            acc3 += a.x * q3.x + a.y * q3.y + a.z * q3.z + a.w * q3.w;
        }
        __syncthreads();
    }

    int idx = tid & 63;
    if (ks > 0) {
        red[ks - 1][idx][0] = acc0; red[ks - 1][idx][1] = acc1;
        red[ks - 1][idx][2] = acc2; red[ks - 1][idx][3] = acc3;
    }
    __syncthreads();
    if (ks == 0) {
        #pragma unroll
        for (int r = 0; r < 3; ++r) {
            acc0 += red[r][idx][0]; acc1 += red[r][idx][1];
            acc2 += red[r][idx][2]; acc3 += red[r][idx][3];
        }
        float co = c1c[b * H_ + j];
        float cn = sigm(acc1) * co + sigm(acc0) * tanh_(acc2);
        float hn = sigm(acc3) * tanh_(cn);
        c1n[b * H_ + j] = cn;
        h1n[b * H_ + j] = hn;
    }
}

__global__ __launch_bounds__(256) void k_q(
    const float* __restrict__ w_in, const float* __restrict__ h1n,
    float* __restrict__ q_out)
{
    __shared__ float As[4][32][68];
    __shared__ float red[3][64];

    int tid = threadIdx.x;
    int b  = tid & 31;
    int jl = (tid >> 5) & 1;
    int ks = tid >> 6;
    int j  = blockIdx.x * 2 + jl;

    float acc = 0.0f;
    for (int c = 0; c < 4; ++c) {
        #pragma unroll
        for (int i = 0; i < 8; ++i) {
            int q   = tid + i * 256;
            int ksq = q >> 9;
            int rem = q & 511;
            int bb  = rem >> 4;
            int kq  = rem & 15;
            int kg  = ksq * 256 + c * 64 + kq * 4;
            *(float4*)&As[ksq][bb][kq * 4] = *(const float4*)(h1n + (size_t)bb * H_ + kg);
        }
        __syncthreads();

        int kbase = ks * 256 + c * 64;
        const float4* w0 = (const float4*)(w_in + (size_t)j * H_ + kbase);
        const float4* A4 = (const float4*)&As[ks][b][0];
        #pragma unroll
        for (int kk = 0; kk < 16; ++kk) {
            float4 a  = A4[kk];
            float4 q0 = w0[kk];
            acc += a.x * q0.x + a.y * q0.y + a.z * q0.z + a.w * q0.w;
        }
        __syncthreads();
    }

    int idx = tid & 63;
    if (ks > 0) red[ks - 1][idx] = acc;
    __syncthreads();
    if (ks == 0) {
        acc += red[0][idx] + red[1][idx] + red[2][idx];
        q_out[b * H_ + j] = acc;
    }
}

__global__ __launch_bounds__(256) void k_out(
    const float* __restrict__ w_out, const float* __restrict__ ctx,
    const float* __restrict__ h1n,
    float* __restrict__ feedn, float* __restrict__ dout, int t)
{
    __shared__ float As[4][32][68];
    __shared__ float red[3][64];

    int tid = threadIdx.x;
    int b  = tid & 31;
    int jl = (tid >> 5) & 1;
    int ks = tid >> 6;
    int j  = blockIdx.x * 2 + jl;

    float acc = 0.0f;
    for (int c = 0; c < 8; ++c) {
        #pragma unroll
        for (int i = 0; i < 8; ++i) {
            int q   = tid + i * 256;
            int ksq = q >> 9;
            int rem = q & 511;
            int bb  = rem >> 4;
            int kq  = rem & 15;
            int kg  = ksq * 512 + c * 64 + kq * 4;
            const float* src = (kg < 1024) ? (ctx + (size_t)bb * H_ + kg)
                                           : (h1n + (size_t)bb * H_ + (kg - 1024));
            *(float4*)&As[ksq][bb][kq * 4] = *(const float4*)src;
        }
        __syncthreads();

        int kbase = ks * 512 + c * 64;
        const float4* w0 = (const float4*)(w_out + (size_t)j * 2048 + kbase);
        const float4* A4 = (const float4*)&As[ks][b][0];
        #pragma unroll
        for (int kk = 0; kk < 16; ++kk) {
            float4 a  = A4[kk];
            float4 q0 = w0[kk];
            acc += a.x * q0.x + a.y * q0.y + a.z * q0.z + a.w * q0.w;
        }
        __syncthreads();
    }

    int idx = tid & 63;
    if (ks > 0) red[ks - 1][idx] = acc;
    __syncthreads();
    if (ks == 0) {
        acc += red[0][idx] + red[1][idx] + red[2][idx];
        float o = tanh_(acc);
        feedn[b * H_ + j] = o;
        dout[((size_t)b * T_ + t) * H_ + j] = o;
    }
}

// ---------------------------------------------------------------------------
extern "C" void kernel_launch(void* const* d_in, const int* in_sizes, int n_in,
                              void* d_out, int out_size, void* d_ws, size_t ws_size,
                              hipStream_t stream) {
    const int*   tgt    = (const int*)  d_in[0];
    const float* mem    = (const float*)d_in[1];
    const int*   masks  = (const int*)  d_in[2];
    const float* h0in   = (const float*)d_in[3];
    const float* c0in   = (const float*)d_in[4];
    const float* emb    = (const float*)d_in[5];
    const float* w_ih0  = (const float*)d_in[6];
    const float* w_hh0  = (const float*)d_in[7];
    const float* b_ih0  = (const float*)d_in[8];
    const float* b_hh0  = (const float*)d_in[9];
    const float* w_ih1  = (const float*)d_in[10];
    const float* w_hh1  = (const float*)d_in[11];
    const float* b_ih1  = (const float*)d_in[12];
    const float* b_hh1  = (const float*)d_in[13];
    const float* w_in   = (const float*)d_in[14];
    const float* w_out  = (const float*)d_in[15];

    float* dout     = (float*)d_out;
    float* attn_out = dout + (size_t)B_ * T_ * H_;

    // ---- bf16 workspace layout ----
    const size_t nwb0 = (size_t)4096 * 2560;   // lstm0 packed weights (bf16)
    const size_t nwb1 = (size_t)4096 * 2048;   // lstm1
    const size_t nwq  = (size_t)1024 * 1024;   // w_in
    const size_t nwo  = (size_t)1024 * 2048;   // w_out
    const size_t wbytes = (nwb0 + nwb1 + nwq + nwo) * sizeof(unsigned short);
    const size_t fbytes = (size_t)(2+2+2+2+2) * BH_ * 4 + (size_t)2 * BH_ * 4
                        + (size_t)B_ * S_ * 4 + 256;   // states+qbuf+ctxb+scw+len
    const bool use_bf16 = (ws_size >= wbytes + fbytes);

    if (use_bf16) {
        unsigned short* wb0 = (unsigned short*)d_ws;
        unsigned short* wb1 = wb0 + nwb0;
        unsigned short* wq  = wb1 + nwb1;
        unsigned short* wo  = wq  + nwq;
        float* fs   = (float*)(wo + nwo);
        float* h0s  = fs;                  // [2][B*H]
        float* h1s  = h0s + 2 * BH_;
        float* c0s  = h1s + 2 * BH_;
        float* c1s  = c0s + 2 * BH_;
        float* feed = c1s + 2 * BH_;
        float* qbuf = feed + 2 * BH_;      // [B*H]
        float* ctxb = qbuf + BH_;          // [B*H]
        float* scw  = ctxb + BH_;          // [B*S]

        // per-call weight conversion (graph-deterministic)
        k_cvt2<<<4096, 256, 0, stream>>>(w_ih0, w_hh0, wb0, 1536, 1024);
        k_cvt2<<<4096, 256, 0, stream>>>(w_ih1, w_hh1, wb1, 1024, 1024);
        k_cvt2<<<1024, 256, 0, stream>>>(w_in,  w_in,  wq,  1024, 0);
        k_cvt2<<<1024, 256, 0, stream>>>(w_out, w_out, wo,  2048, 0);
        k_init<<<128, 256, 0, stream>>>(h0in, c0in, h0s, c0s, h1s, c1s, feed);

        for (int t = 0; t < T_; ++t) {
            int cur = t & 1, nxt = cur ^ 1;
            k_lstm0b<<<512, 512, 0, stream>>>(tgt, emb, wb0, b_ih0, b_hh0,
                                              feed + cur * BH_, h0s + cur * BH_, c0s + cur * BH_,
                                              h0s + nxt * BH_, c0s + nxt * BH_, t);
            k_lstm1b<<<512, 512, 0, stream>>>(wb1, b_ih1, b_hh1,
                                              h0s + nxt * BH_, h1s + cur * BH_, c1s + cur * BH_,
                                              h1s + nxt * BH_, c1s + nxt * BH_);
            k_qb<<<512, 512, 0, stream>>>(wq, h1s + nxt * BH_, qbuf);
            k_scores<<<512, 256, 0, stream>>>(qbuf, mem, scw);
            k_ctx<<<512, 256, 0, stream>>>(scw, mem, masks, ctxb, attn_out, t);
            k_outb<<<512, 512, 0, stream>>>(wo, ctxb, h1s + nxt * BH_,
                                            feed + nxt * BH_, dout, t);
        }
    } else {
        // -------- f32 fallback (round-2 pipeline) --------
        float* ws   = (float*)d_ws;
        float* h0s  = ws;
        float* c0s  = h0s  + 2 * BH_;
        float* h1s  = c0s  + 2 * BH_;
        float* c1s  = h1s  + 2 * BH_;
        float* feed = c1s  + 2 * BH_;
        float* qctx = feed + 2 * BH_;
        float* scw  = qctx + BH_;

        k_init<<<128, 256, 0, stream>>>(h0in, c0in, h0s, c0s, h1s, c1s, feed);
        for (int t = 0; t < T_; ++t) {
            int cur = t & 1, nxt = cur ^ 1;
            k_lstm0<<<512, 256, 0, stream>>>(tgt, emb, w_ih0, w_hh0, b_ih0, b_hh0,
                                             feed + cur * BH_, h0s + cur * BH_, c0s + cur * BH_,
                                             h0s + nxt * BH_, c0s + nxt * BH_, t);
            k_lstm1<<<512, 256, 0, stream>>>(w_ih1, w_hh1, b_ih1, b_hh1,
                                             h0s + nxt * BH_, h1s + cur * BH_, c1s + cur * BH_,
                                             h1s + nxt * BH_, c1s + nxt * BH_);
            k_q<<<512, 256, 0, stream>>>(w_in, h1s + nxt * BH_, qctx);
            k_scores<<<512, 256, 0, stream>>>(qctx, mem, scw);
            k_ctx<<<512, 256, 0, stream>>>(scw, mem, masks, qctx, attn_out, t);
            k_out<<<512, 256, 0, stream>>>(w_out, qctx, h1s + nxt * BH_,
                                           feed + nxt * BH_, dout, t);
        }
    }
}

// Round 6
// 9521.205 us; speedup vs baseline: 3.2991x; 2.6876x over previous
//
#include <hip/hip_runtime.h>
#include <math.h>

#define B_ 32
#define T_ 64
#define S_ 256
#define H_ 1024
#define E_ 512
#define BH_ (B_ * H_)

__device__ __forceinline__ float sigm(float x) {
    return 1.0f / (1.0f + __expf(-x));
}
__device__ __forceinline__ float tanh_(float x) {
    x = fminf(15.0f, fmaxf(-15.0f, x));
    float e = __expf(-2.0f * x);
    return (1.0f - e) / (1.0f + e);
}

// ---------------------------------------------------------------------------
// init: state ping-pong slot 0 + zero input feed
// ---------------------------------------------------------------------------
__global__ void k_init(const float* __restrict__ h0in, const float* __restrict__ c0in,
                       float* h0s, float* c0s, float* h1s, float* c1s, float* feed) {
    int i = blockIdx.x * 256 + threadIdx.x;
    if (i < BH_) {
        h0s[i]  = h0in[i];
        h1s[i]  = h0in[BH_ + i];
        c0s[i]  = c0in[i];
        c1s[i]  = c0in[BH_ + i];
        feed[i] = 0.0f;
    }
}

// ===========================================================================
// f32 GEMM kernels, high-occupancy form:
//   grid 1024 (j = blockIdx.x), block 256 = 32 b x 8 ks, 4 blocks/CU.
//   A (activations) staged in 32-k chunks: As[8 ks][32 b][36 pad], 36.9 KB.
//   Weight rows read from d_in (f32), 16B loads, per-half-wave broadcast.
// ===========================================================================

// -------- LSTM layer 0: K = 2560 = [emb 512 | feed 1024 | h0 1024] ---------
__global__ __launch_bounds__(256, 4) void k_lstm0c(
    const int* __restrict__ tgt, const float* __restrict__ emb,
    const float* __restrict__ w_ih0, const float* __restrict__ w_hh0,
    const float* __restrict__ b_ih0, const float* __restrict__ b_hh0,
    const float* __restrict__ feed, const float* __restrict__ h0c,
    const float* __restrict__ c0c,
    float* __restrict__ h0n, float* __restrict__ c0n, int t)
{
    __shared__ float As[8][32][36];     // 36,864 B
    __shared__ int   tok[32];

    const int tid = threadIdx.x;
    const int b  = tid & 31;
    const int ks = tid >> 5;            // 0..7
    const int j  = blockIdx.x;

    if (tid < 32) tok[tid] = tgt[tid * T_ + t];
    __syncthreads();

    float acc0, acc1, acc2, acc3;
    if (ks == 0) {
        acc0 = b_ih0[0 * H_ + j] + b_hh0[0 * H_ + j];
        acc1 = b_ih0[1 * H_ + j] + b_hh0[1 * H_ + j];
        acc2 = b_ih0[2 * H_ + j] + b_hh0[2 * H_ + j];
        acc3 = b_ih0[3 * H_ + j] + b_hh0[3 * H_ + j];
    } else {
        acc0 = acc1 = acc2 = acc3 = 0.0f;
    }

    for (int c = 0; c < 10; ++c) {
        // stage [8 ks][32 b][32 k] floats = 2048 float4, 8 per thread
        #pragma unroll
        for (int i = 0; i < 8; ++i) {
            int s   = tid + i * 256;
            int kss = s >> 8;            // 0..7
            int rem = s & 255;
            int bb  = rem >> 3;          // 0..31
            int kq  = rem & 7;           // 0..7
            int kg  = kss * 320 + c * 32 + kq * 4;
            const float* src;
            if (kg < 512)        src = emb  + (size_t)tok[bb] * E_ + kg;
            else if (kg < 1536)  src = feed + (size_t)bb * H_ + (kg - 512);
            else                 src = h0c  + (size_t)bb * H_ + (kg - 1536);
            *(float4*)&As[kss][bb][kq * 4] = *(const float4*)src;
        }
        __syncthreads();

        int kbase = ks * 320 + c * 32;
        const float4 *w0, *w1, *w2, *w3;
        if (kbase < 1536) {
            w0 = (const float4*)(w_ih0 + (size_t)(0 * H_ + j) * 1536 + kbase);
            w1 = (const float4*)(w_ih0 + (size_t)(1 * H_ + j) * 1536 + kbase);
            w2 = (const float4*)(w_ih0 + (size_t)(2 * H_ + j) * 1536 + kbase);
            w3 = (const float4*)(w_ih0 + (size_t)(3 * H_ + j) * 1536 + kbase);
        } else {
            int kb = kbase - 1536;
            w0 = (const float4*)(w_hh0 + (size_t)(0 * H_ + j) * 1024 + kb);
            w1 = (const float4*)(w_hh0 + (size_t)(1 * H_ + j) * 1024 + kb);
            w2 = (const float4*)(w_hh0 + (size_t)(2 * H_ + j) * 1024 + kb);
            w3 = (const float4*)(w_hh0 + (size_t)(3 * H_ + j) * 1024 + kb);
        }
        const float4* A4 = (const float4*)&As[ks][b][0];
        #pragma unroll
        for (int kk = 0; kk < 8; ++kk) {
            float4 a  = A4[kk];
            float4 q0 = w0[kk], q1 = w1[kk], q2 = w2[kk], q3 = w3[kk];
            acc0 += a.x * q0.x + a.y * q0.y + a.z * q0.z + a.w * q0.w;
            acc1 += a.x * q1.x + a.y * q1.y + a.z * q1.z + a.w * q1.w;
            acc2 += a.x * q2.x + a.y * q2.y + a.z * q2.z + a.w * q2.w;
            acc3 += a.x * q3.x + a.y * q3.y + a.z * q3.z + a.w * q3.w;
        }
        __syncthreads();
    }

    float* redp = (float*)&As[0][0][0];   // As dead; alias for reduction
    if (ks > 0) {
        int base = (((ks - 1) * 32) + b) * 4;
        redp[base + 0] = acc0; redp[base + 1] = acc1;
        redp[base + 2] = acc2; redp[base + 3] = acc3;
    }
    __syncthreads();
    if (ks == 0) {
        #pragma unroll
        for (int r = 0; r < 7; ++r) {
            int base = ((r * 32) + b) * 4;
            acc0 += redp[base + 0]; acc1 += redp[base + 1];
            acc2 += redp[base + 2]; acc3 += redp[base + 3];
        }
        float co = c0c[b * H_ + j];
        float cn = sigm(acc1) * co + sigm(acc0) * tanh_(acc2);
        c0n[b * H_ + j] = cn;
        h0n[b * H_ + j] = sigm(acc3) * tanh_(cn);
    }
}

// -------- LSTM layer 1: K = 2048 = [h0n 1024 | h1 1024] --------------------
__global__ __launch_bounds__(256, 4) void k_lstm1c(
    const float* __restrict__ w_ih1, const float* __restrict__ w_hh1,
    const float* __restrict__ b_ih1, const float* __restrict__ b_hh1,
    const float* __restrict__ x, const float* __restrict__ h1c,
    const float* __restrict__ c1c,
    float* __restrict__ h1n, float* __restrict__ c1n)
{
    __shared__ float As[8][32][36];

    const int tid = threadIdx.x;
    const int b  = tid & 31;
    const int ks = tid >> 5;
    const int j  = blockIdx.x;

    float acc0, acc1, acc2, acc3;
    if (ks == 0) {
        acc0 = b_ih1[0 * H_ + j] + b_hh1[0 * H_ + j];
        acc1 = b_ih1[1 * H_ + j] + b_hh1[1 * H_ + j];
        acc2 = b_ih1[2 * H_ + j] + b_hh1[2 * H_ + j];
        acc3 = b_ih1[3 * H_ + j] + b_hh1[3 * H_ + j];
    } else {
        acc0 = acc1 = acc2 = acc3 = 0.0f;
    }

    for (int c = 0; c < 8; ++c) {
        #pragma unroll
        for (int i = 0; i < 8; ++i) {
            int s   = tid + i * 256;
            int kss = s >> 8;
            int rem = s & 255;
            int bb  = rem >> 3;
            int kq  = rem & 7;
            int kg  = kss * 256 + c * 32 + kq * 4;
            const float* src = (kg < 1024) ? (x + (size_t)bb * H_ + kg)
                                           : (h1c + (size_t)bb * H_ + (kg - 1024));
            *(float4*)&As[kss][bb][kq * 4] = *(const float4*)src;
        }
        __syncthreads();

        int kbase = ks * 256 + c * 32;
        const float* wb;
        int ko;
        if (kbase < 1024) { wb = w_ih1; ko = kbase; }
        else              { wb = w_hh1; ko = kbase - 1024; }
        const float4* w0 = (const float4*)(wb + (size_t)(0 * H_ + j) * H_ + ko);
        const float4* w1 = (const float4*)(wb + (size_t)(1 * H_ + j) * H_ + ko);
        const float4* w2 = (const float4*)(wb + (size_t)(2 * H_ + j) * H_ + ko);
        const float4* w3 = (const float4*)(wb + (size_t)(3 * H_ + j) * H_ + ko);
        const float4* A4 = (const float4*)&As[ks][b][0];
        #pragma unroll
        for (int kk = 0; kk < 8; ++kk) {
            float4 a  = A4[kk];
            float4 q0 = w0[kk], q1 = w1[kk], q2 = w2[kk], q3 = w3[kk];
            acc0 += a.x * q0.x + a.y * q0.y + a.z * q0.z + a.w * q0.w;
            acc1 += a.x * q1.x + a.y * q1.y + a.z * q1.z + a.w * q1.w;
            acc2 += a.x * q2.x + a.y * q2.y + a.z * q2.z + a.w * q2.w;
            acc3 += a.x * q3.x + a.y * q3.y + a.z * q3.z + a.w * q3.w;
        }
        __syncthreads();
    }

    float* redp = (float*)&As[0][0][0];
    if (ks > 0) {
        int base = (((ks - 1) * 32) + b) * 4;
        redp[base + 0] = acc0; redp[base + 1] = acc1;
        redp[base + 2] = acc2; redp[base + 3] = acc3;
    }
    __syncthreads();
    if (ks == 0) {
        #pragma unroll
        for (int r = 0; r < 7; ++r) {
            int base = ((r * 32) + b) * 4;
            acc0 += redp[base + 0]; acc1 += redp[base + 1];
            acc2 += redp[base + 2]; acc3 += redp[base + 3];
        }
        float co = c1c[b * H_ + j];
        float cn = sigm(acc1) * co + sigm(acc0) * tanh_(acc2);
        c1n[b * H_ + j] = cn;
        h1n[b * H_ + j] = sigm(acc3) * tanh_(cn);
    }
}

// -------- q = h1n @ w_in^T : K = 1024, 1 gate ------------------------------
__global__ __launch_bounds__(256, 4) void k_qc(
    const float* __restrict__ w_in, const float* __restrict__ h1n,
    float* __restrict__ q_out)
{
    __shared__ float As[8][32][36];

    const int tid = threadIdx.x;
    const int b  = tid & 31;
    const int ks = tid >> 5;
    const int j  = blockIdx.x;

    float acc = 0.0f;
    for (int c = 0; c < 4; ++c) {
        #pragma unroll
        for (int i = 0; i < 8; ++i) {
            int s   = tid + i * 256;
            int kss = s >> 8;
            int rem = s & 255;
            int bb  = rem >> 3;
            int kq  = rem & 7;
            int kg  = kss * 128 + c * 32 + kq * 4;
            *(float4*)&As[kss][bb][kq * 4] = *(const float4*)(h1n + (size_t)bb * H_ + kg);
        }
        __syncthreads();

        const float4* w0 = (const float4*)(w_in + (size_t)j * H_ + ks * 128 + c * 32);
        const float4* A4 = (const float4*)&As[ks][b][0];
        #pragma unroll
        for (int kk = 0; kk < 8; ++kk) {
            float4 a  = A4[kk];
            float4 q0 = w0[kk];
            acc += a.x * q0.x + a.y * q0.y + a.z * q0.z + a.w * q0.w;
        }
        __syncthreads();
    }

    float* redp = (float*)&As[0][0][0];
    if (ks > 0) redp[(ks - 1) * 32 + b] = acc;
    __syncthreads();
    if (ks == 0) {
        #pragma unroll
        for (int r = 0; r < 7; ++r) acc += redp[r * 32 + b];
        q_out[b * H_ + j] = acc;
    }
}

// -------- out = tanh([ctx | h1n] @ w_out^T) : K = 2048, 1 gate -------------
__global__ __launch_bounds__(256, 4) void k_outc(
    const float* __restrict__ w_out, const float* __restrict__ ctx,
    const float* __restrict__ h1n,
    float* __restrict__ feedn, float* __restrict__ dout, int t)
{
    __shared__ float As[8][32][36];

    const int tid = threadIdx.x;
    const int b  = tid & 31;
    const int ks = tid >> 5;
    const int j  = blockIdx.x;

    float acc = 0.0f;
    for (int c = 0; c < 8; ++c) {
        #pragma unroll
        for (int i = 0; i < 8; ++i) {
            int s   = tid + i * 256;
            int kss = s >> 8;
            int rem = s & 255;
            int bb  = rem >> 3;
            int kq  = rem & 7;
            int kg  = kss * 256 + c * 32 + kq * 4;
            const float* src = (kg < 1024) ? (ctx + (size_t)bb * H_ + kg)
                                           : (h1n + (size_t)bb * H_ + (kg - 1024));
            *(float4*)&As[kss][bb][kq * 4] = *(const float4*)src;
        }
        __syncthreads();

        const float4* w0 = (const float4*)(w_out + (size_t)j * 2048 + ks * 256 + c * 32);
        const float4* A4 = (const float4*)&As[ks][b][0];
        #pragma unroll
        for (int kk = 0; kk < 8; ++kk) {
            float4 a  = A4[kk];
            float4 q0 = w0[kk];
            acc += a.x * q0.x + a.y * q0.y + a.z * q0.z + a.w * q0.w;
        }
        __syncthreads();
    }

    float* redp = (float*)&As[0][0][0];
    if (ks > 0) redp[(ks - 1) * 32 + b] = acc;
    __syncthreads();
    if (ks == 0) {
        #pragma unroll
        for (int r = 0; r < 7; ++r) acc += redp[r * 32 + b];
        float o = tanh_(acc);
        feedn[b * H_ + j] = o;
        dout[((size_t)b * T_ + t) * H_ + j] = o;
    }
}

// ---------------------------------------------------------------------------
// scores[b][s] = q[b] . mem[b][s]   grid 512 = b(32) x stile(16), block 256
// ---------------------------------------------------------------------------
__global__ __launch_bounds__(256) void k_scores(
    const float* __restrict__ q_in, const float* __restrict__ mem,
    float* __restrict__ sc_out)
{
    __shared__ float q_lds[1024];

    int b  = blockIdx.x >> 4;
    int st = blockIdx.x & 15;
    int tid  = threadIdx.x;
    int lane = tid & 63;
    int wv   = tid >> 6;

    ((float4*)q_lds)[tid] = ((const float4*)(q_in + (size_t)b * H_))[tid];
    __syncthreads();

    float4 q4[4];
    #pragma unroll
    for (int i = 0; i < 4; ++i) q4[i] = ((const float4*)q_lds)[lane + 64 * i];

    const float* mb = mem + (size_t)b * S_ * H_;
    #pragma unroll
    for (int ss = 0; ss < 4; ++ss) {
        int s = st * 16 + wv * 4 + ss;
        const float4* mr = (const float4*)(mb + (size_t)s * H_);
        float a = 0.0f;
        #pragma unroll
        for (int i = 0; i < 4; ++i) {
            float4 m = mr[lane + 64 * i];
            a += q4[i].x * m.x + q4[i].y * m.y + q4[i].z * m.z + q4[i].w * m.w;
        }
        #pragma unroll
        for (int o = 32; o > 0; o >>= 1) a += __shfl_down(a, o);
        if (lane == 0) sc_out[b * S_ + s] = a;
    }
}

// ---------------------------------------------------------------------------
// ctx: local masked softmax of scores + weighted sum.  grid 512, block 256
// ---------------------------------------------------------------------------
__global__ __launch_bounds__(256) void k_ctx(
    const float* __restrict__ sc_in, const float* __restrict__ mem,
    const int* __restrict__ masks,
    float* __restrict__ ctx, float* __restrict__ attn_out, int t)
{
    __shared__ float aw[256];
    __shared__ float red2[4][64];

    int b  = blockIdx.x >> 4;
    int ht = blockIdx.x & 15;
    int tid  = threadIdx.x;
    int lane = tid & 63;
    int wv   = tid >> 6;

    if (wv == 0) {
        int m = 0;
        #pragma unroll
        for (int i = 0; i < 4; ++i) m += masks[b * S_ + lane * 4 + i];
        #pragma unroll
        for (int o = 32; o > 0; o >>= 1) m += __shfl_down(m, o);
        int len = __shfl(m, 0);

        float v[4];
        float mx = -1e30f;
        #pragma unroll
        for (int i = 0; i < 4; ++i) {
            int s = lane + 64 * i;
            float xv = (s < len) ? sc_in[b * S_ + s] : -1e9f;
            v[i] = xv;
            mx = fmaxf(mx, xv);
        }
        #pragma unroll
        for (int o = 32; o > 0; o >>= 1) mx = fmaxf(mx, __shfl_xor(mx, o));
        float sm = 0.0f;
        #pragma unroll
        for (int i = 0; i < 4; ++i) { v[i] = __expf(v[i] - mx); sm += v[i]; }
        #pragma unroll
        for (int o = 32; o > 0; o >>= 1) sm += __shfl_xor(sm, o);
        float inv = 1.0f / sm;
        #pragma unroll
        for (int i = 0; i < 4; ++i) {
            int s = lane + 64 * i;
            float w = v[i] * inv;
            aw[s] = w;
            if (ht == 0) attn_out[((size_t)b * T_ + t) * S_ + s] = w;
        }
    }
    __syncthreads();

    int h = ht * 64 + lane;
    const float* mb = mem + (size_t)b * S_ * H_;
    float a = 0.0f;
    #pragma unroll 8
    for (int ss = 0; ss < 64; ++ss) {
        int s = wv * 64 + ss;
        a += aw[s] * mb[(size_t)s * H_ + h];
    }
    red2[wv][lane] = a;
    __syncthreads();
    if (tid < 64) {
        float r = red2[0][tid] + red2[1][tid] + red2[2][tid] + red2[3][tid];
        ctx[b * H_ + ht * 64 + tid] = r;
    }
}

// ---------------------------------------------------------------------------
extern "C" void kernel_launch(void* const* d_in, const int* in_sizes, int n_in,
                              void* d_out, int out_size, void* d_ws, size_t ws_size,
                              hipStream_t stream) {
    const int*   tgt    = (const int*)  d_in[0];
    const float* mem    = (const float*)d_in[1];
    const int*   masks  = (const int*)  d_in[2];
    const float* h0in   = (const float*)d_in[3];
    const float* c0in   = (const float*)d_in[4];
    const float* emb    = (const float*)d_in[5];
    const float* w_ih0  = (const float*)d_in[6];
    const float* w_hh0  = (const float*)d_in[7];
    const float* b_ih0  = (const float*)d_in[8];
    const float* b_hh0  = (const float*)d_in[9];
    const float* w_ih1  = (const float*)d_in[10];
    const float* w_hh1  = (const float*)d_in[11];
    const float* b_ih1  = (const float*)d_in[12];
    const float* b_hh1  = (const float*)d_in[13];
    const float* w_in   = (const float*)d_in[14];
    const float* w_out  = (const float*)d_in[15];

    float* dout     = (float*)d_out;
    float* attn_out = dout + (size_t)B_ * T_ * H_;

    float* ws   = (float*)d_ws;
    float* h0s  = ws;              // [2][B*H]
    float* c0s  = h0s  + 2 * BH_;  // [2][B*H]
    float* h1s  = c0s  + 2 * BH_;  // [2][B*H]
    float* c1s  = h1s  + 2 * BH_;  // [2][B*H]
    float* feed = c1s  + 2 * BH_;  // [2][B*H]
    float* qctx = feed + 2 * BH_;  // [B*H]  (q, then aliased as ctx)
    float* scw  = qctx + BH_;      // [B*S]

    k_init<<<128, 256, 0, stream>>>(h0in, c0in, h0s, c0s, h1s, c1s, feed);

    for (int t = 0; t < T_; ++t) {
        int cur = t & 1, nxt = cur ^ 1;
        k_lstm0c<<<1024, 256, 0, stream>>>(tgt, emb, w_ih0, w_hh0, b_ih0, b_hh0,
                                           feed + cur * BH_, h0s + cur * BH_, c0s + cur * BH_,
                                           h0s + nxt * BH_, c0s + nxt * BH_, t);
        k_lstm1c<<<1024, 256, 0, stream>>>(w_ih1, w_hh1, b_ih1, b_hh1,
                                           h0s + nxt * BH_, h1s + cur * BH_, c1s + cur * BH_,
                                           h1s + nxt * BH_, c1s + nxt * BH_);
        k_qc<<<1024, 256, 0, stream>>>(w_in, h1s + nxt * BH_, qctx);
        k_scores<<<512, 256, 0, stream>>>(qctx, mem, scw);
        k_ctx<<<512, 256, 0, stream>>>(scw, mem, masks, qctx, attn_out, t);
        k_outc<<<1024, 256, 0, stream>>>(w_out, qctx, h1s + nxt * BH_,
                                         feed + nxt * BH_, dout, t);
    }
}

// Round 7
// 8032.882 us; speedup vs baseline: 3.9103x; 1.1853x over previous
//
#include <hip/hip_runtime.h>
#include <math.h>

#define B_ 32
#define T_ 64
#define S_ 256
#define H_ 1024
#define E_ 512
#define BH_ (B_ * H_)

__device__ __forceinline__ float sigm(float x) {
    return 1.0f / (1.0f + __expf(-x));
}
__device__ __forceinline__ float tanh_(float x) {
    x = fminf(15.0f, fmaxf(-15.0f, x));
    float e = __expf(-2.0f * x);
    return (1.0f - e) / (1.0f + e);
}

// ---------------------------------------------------------------------------
// init: state ping-pong slot 0 + zero input feed
// ---------------------------------------------------------------------------
__global__ void k_init(const float* __restrict__ h0in, const float* __restrict__ c0in,
                       float* h0s, float* c0s, float* h1s, float* c1s, float* feed) {
    int i = blockIdx.x * 256 + threadIdx.x;
    if (i < BH_) {
        h0s[i]  = h0in[i];
        h1s[i]  = h0in[BH_ + i];
        c0s[i]  = c0in[i];
        c1s[i]  = c0in[BH_ + i];
        feed[i] = 0.0f;
    }
}

// ---------------------------------------------------------------------------
// pmem[r][k] = sum_j mem[r][j] * w_in[j][k]   (r = b*S+s; time-invariant)
// grid (128, 16), block 256.  64x64 tile, K-chunk 32, 4x4 outputs/thread.
// ---------------------------------------------------------------------------
__global__ __launch_bounds__(256) void k_pmem(
    const float* __restrict__ mem, const float* __restrict__ w_in,
    float* __restrict__ pmem)
{
    __shared__ float As[64][36];   // [row][k]  +pad
    __shared__ float Bs[32][68];   // [k][col]  +pad

    const int tid = threadIdx.x;
    const int rt = blockIdx.x * 64;
    const int ct = blockIdx.y * 64;
    const int tx = tid & 15;       // col group
    const int ty = tid >> 4;       // row group

    float acc[4][4] = {{0.f}};

    for (int jc = 0; jc < 1024; jc += 32) {
        #pragma unroll
        for (int i = 0; i < 2; ++i) {
            int s2  = tid + i * 256;            // 0..511
            int row = s2 >> 3, kq = s2 & 7;
            *(float4*)&As[row][kq * 4] =
                *(const float4*)(mem + (size_t)(rt + row) * 1024 + jc + kq * 4);
        }
        #pragma unroll
        for (int i = 0; i < 2; ++i) {
            int s2 = tid + i * 256;
            int kk = s2 >> 4, cq = s2 & 15;
            *(float4*)&Bs[kk][cq * 4] =
                *(const float4*)(w_in + (size_t)(jc + kk) * 1024 + ct + cq * 4);
        }
        __syncthreads();

        #pragma unroll
        for (int kk = 0; kk < 32; ++kk) {
            float a0 = As[ty * 4 + 0][kk], a1 = As[ty * 4 + 1][kk];
            float a2 = As[ty * 4 + 2][kk], a3 = As[ty * 4 + 3][kk];
            float b0 = Bs[kk][tx * 4 + 0], b1 = Bs[kk][tx * 4 + 1];
            float b2 = Bs[kk][tx * 4 + 2], b3 = Bs[kk][tx * 4 + 3];
            acc[0][0] += a0 * b0; acc[0][1] += a0 * b1; acc[0][2] += a0 * b2; acc[0][3] += a0 * b3;
            acc[1][0] += a1 * b0; acc[1][1] += a1 * b1; acc[1][2] += a1 * b2; acc[1][3] += a1 * b3;
            acc[2][0] += a2 * b0; acc[2][1] += a2 * b1; acc[2][2] += a2 * b2; acc[2][3] += a2 * b3;
            acc[3][0] += a3 * b0; acc[3][1] += a3 * b1; acc[3][2] += a3 * b2; acc[3][3] += a3 * b3;
        }
        __syncthreads();
    }

    #pragma unroll
    for (int i = 0; i < 4; ++i) {
        float4 v = make_float4(acc[i][0], acc[i][1], acc[i][2], acc[i][3]);
        *(float4*)(pmem + (size_t)(rt + ty * 4 + i) * 1024 + ct + tx * 4) = v;
    }
}

// ===========================================================================
// Round-2 GEMM bodies (proven): grid 512, block 256 = 32 b x 2 jl x 4 ks.
// ===========================================================================

// -------- LSTM layer 0: K = 2560 = [emb 512 | feed 1024 | h0 1024] ---------
__global__ __launch_bounds__(256) void k_lstm0(
    const int* __restrict__ tgt, const float* __restrict__ emb,
    const float* __restrict__ w_ih0, const float* __restrict__ w_hh0,
    const float* __restrict__ b_ih0, const float* __restrict__ b_hh0,
    const float* __restrict__ feed, const float* __restrict__ h0c,
    const float* __restrict__ c0c,
    float* __restrict__ h0n, float* __restrict__ c0n, int t)
{
    __shared__ float As[4][32][68];
    __shared__ float red[3][64][4];
    __shared__ int   tok[32];

    int tid = threadIdx.x;
    int b  = tid & 31;
    int jl = (tid >> 5) & 1;
    int ks = tid >> 6;
    int j  = blockIdx.x * 2 + jl;

    if (tid < 32) tok[tid] = tgt[tid * T_ + t];
    __syncthreads();

    float acc0, acc1, acc2, acc3;
    if (ks == 0) {
        acc0 = b_ih0[0 * H_ + j] + b_hh0[0 * H_ + j];
        acc1 = b_ih0[1 * H_ + j] + b_hh0[1 * H_ + j];
        acc2 = b_ih0[2 * H_ + j] + b_hh0[2 * H_ + j];
        acc3 = b_ih0[3 * H_ + j] + b_hh0[3 * H_ + j];
    } else {
        acc0 = acc1 = acc2 = acc3 = 0.0f;
    }

    for (int c = 0; c < 10; ++c) {
        #pragma unroll
        for (int i = 0; i < 8; ++i) {
            int q   = tid + i * 256;
            int ksq = q >> 9;
            int rem = q & 511;
            int bb  = rem >> 4;
            int kq  = rem & 15;
            int kg  = ksq * 640 + c * 64 + kq * 4;
            const float* src;
            if (kg < 512)        src = emb  + (size_t)tok[bb] * E_ + kg;
            else if (kg < 1536)  src = feed + (size_t)bb * H_ + (kg - 512);
            else                 src = h0c  + (size_t)bb * H_ + (kg - 1536);
            *(float4*)&As[ksq][bb][kq * 4] = *(const float4*)src;
        }
        __syncthreads();

        int kbase = ks * 640 + c * 64;
        const float4 *w0, *w1, *w2, *w3;
        if (kbase < 1536) {
            w0 = (const float4*)(w_ih0 + (size_t)(0 * H_ + j) * 1536 + kbase);
            w1 = (const float4*)(w_ih0 + (size_t)(1 * H_ + j) * 1536 + kbase);
            w2 = (const float4*)(w_ih0 + (size_t)(2 * H_ + j) * 1536 + kbase);
            w3 = (const float4*)(w_ih0 + (size_t)(3 * H_ + j) * 1536 + kbase);
        } else {
            int kb = kbase - 1536;
            w0 = (const float4*)(w_hh0 + (size_t)(0 * H_ + j) * 1024 + kb);
            w1 = (const float4*)(w_hh0 + (size_t)(1 * H_ + j) * 1024 + kb);
            w2 = (const float4*)(w_hh0 + (size_t)(2 * H_ + j) * 1024 + kb);
            w3 = (const float4*)(w_hh0 + (size_t)(3 * H_ + j) * 1024 + kb);
        }
        const float4* A4 = (const float4*)&As[ks][b][0];
        #pragma unroll
        for (int kk = 0; kk < 16; ++kk) {
            float4 a  = A4[kk];
            float4 q0 = w0[kk], q1 = w1[kk], q2 = w2[kk], q3 = w3[kk];
            acc0 += a.x * q0.x + a.y * q0.y + a.z * q0.z + a.w * q0.w;
            acc1 += a.x * q1.x + a.y * q1.y + a.z * q1.z + a.w * q1.w;
            acc2 += a.x * q2.x + a.y * q2.y + a.z * q2.z + a.w * q2.w;
            acc3 += a.x * q3.x + a.y * q3.y + a.z * q3.z + a.w * q3.w;
        }
        __syncthreads();
    }

    int idx = tid & 63;
    if (ks > 0) {
        red[ks - 1][idx][0] = acc0; red[ks - 1][idx][1] = acc1;
        red[ks - 1][idx][2] = acc2; red[ks - 1][idx][3] = acc3;
    }
    __syncthreads();
    if (ks == 0) {
        #pragma unroll
        for (int r = 0; r < 3; ++r) {
            acc0 += red[r][idx][0]; acc1 += red[r][idx][1];
            acc2 += red[r][idx][2]; acc3 += red[r][idx][3];
        }
        float co = c0c[b * H_ + j];
        float cn = sigm(acc1) * co + sigm(acc0) * tanh_(acc2);
        float hn = sigm(acc3) * tanh_(cn);
        c0n[b * H_ + j] = cn;
        h0n[b * H_ + j] = hn;
    }
}

// -------- LSTM layer 1: K = 2048 = [h0n 1024 | h1 1024] --------------------
__global__ __launch_bounds__(256) void k_lstm1(
    const float* __restrict__ w_ih1, const float* __restrict__ w_hh1,
    const float* __restrict__ b_ih1, const float* __restrict__ b_hh1,
    const float* __restrict__ x, const float* __restrict__ h1c,
    const float* __restrict__ c1c,
    float* __restrict__ h1n, float* __restrict__ c1n)
{
    __shared__ float As[4][32][68];
    __shared__ float red[3][64][4];

    int tid = threadIdx.x;
    int b  = tid & 31;
    int jl = (tid >> 5) & 1;
    int ks = tid >> 6;
    int j  = blockIdx.x * 2 + jl;

    float acc0, acc1, acc2, acc3;
    if (ks == 0) {
        acc0 = b_ih1[0 * H_ + j] + b_hh1[0 * H_ + j];
        acc1 = b_ih1[1 * H_ + j] + b_hh1[1 * H_ + j];
        acc2 = b_ih1[2 * H_ + j] + b_hh1[2 * H_ + j];
        acc3 = b_ih1[3 * H_ + j] + b_hh1[3 * H_ + j];
    } else {
        acc0 = acc1 = acc2 = acc3 = 0.0f;
    }

    for (int c = 0; c < 8; ++c) {
        #pragma unroll
        for (int i = 0; i < 8; ++i) {
            int q   = tid + i * 256;
            int ksq = q >> 9;
            int rem = q & 511;
            int bb  = rem >> 4;
            int kq  = rem & 15;
            int kg  = ksq * 512 + c * 64 + kq * 4;
            const float* src = (kg < 1024) ? (x + (size_t)bb * H_ + kg)
                                           : (h1c + (size_t)bb * H_ + (kg - 1024));
            *(float4*)&As[ksq][bb][kq * 4] = *(const float4*)src;
        }
        __syncthreads();

        int kbase = ks * 512 + c * 64;
        const float* wb;
        int ko;
        if (kbase < 1024) { wb = w_ih1; ko = kbase; }
        else              { wb = w_hh1; ko = kbase - 1024; }
        const float4* w0 = (const float4*)(wb + (size_t)(0 * H_ + j) * H_ + ko);
        const float4* w1 = (const float4*)(wb + (size_t)(1 * H_ + j) * H_ + ko);
        const float4* w2 = (const float4*)(wb + (size_t)(2 * H_ + j) * H_ + ko);
        const float4* w3 = (const float4*)(wb + (size_t)(3 * H_ + j) * H_ + ko);
        const float4* A4 = (const float4*)&As[ks][b][0];
        #pragma unroll
        for (int kk = 0; kk < 16; ++kk) {
            float4 a  = A4[kk];
            float4 q0 = w0[kk], q1 = w1[kk], q2 = w2[kk], q3 = w3[kk];
            acc0 += a.x * q0.x + a.y * q0.y + a.z * q0.z + a.w * q0.w;
            acc1 += a.x * q1.x + a.y * q1.y + a.z * q1.z + a.w * q1.w;
            acc2 += a.x * q2.x + a.y * q2.y + a.z * q2.z + a.w * q2.w;
            acc3 += a.x * q3.x + a.y * q3.y + a.z * q3.z + a.w * q3.w;
        }
        __syncthreads();
    }

    int idx = tid & 63;
    if (ks > 0) {
        red[ks - 1][idx][0] = acc0; red[ks - 1][idx][1] = acc1;
        red[ks - 1][idx][2] = acc2; red[ks - 1][idx][3] = acc3;
    }
    __syncthreads();
    if (ks == 0) {
        #pragma unroll
        for (int r = 0; r < 3; ++r) {
            acc0 += red[r][idx][0]; acc1 += red[r][idx][1];
            acc2 += red[r][idx][2]; acc3 += red[r][idx][3];
        }
        float co = c1c[b * H_ + j];
        float cn = sigm(acc1) * co + sigm(acc0) * tanh_(acc2);
        float hn = sigm(acc3) * tanh_(cn);
        c1n[b * H_ + j] = cn;
        h1n[b * H_ + j] = hn;
    }
}

// -------- q = h1n @ w_in^T (FALLBACK PATH ONLY) ----------------------------
__global__ __launch_bounds__(256) void k_q(
    const float* __restrict__ w_in, const float* __restrict__ h1n,
    float* __restrict__ q_out)
{
    __shared__ float As[4][32][68];
    __shared__ float red[3][64];

    int tid = threadIdx.x;
    int b  = tid & 31;
    int jl = (tid >> 5) & 1;
    int ks = tid >> 6;
    int j  = blockIdx.x * 2 + jl;

    float acc = 0.0f;
    for (int c = 0; c < 4; ++c) {
        #pragma unroll
        for (int i = 0; i < 8; ++i) {
            int q   = tid + i * 256;
            int ksq = q >> 9;
            int rem = q & 511;
            int bb  = rem >> 4;
            int kq  = rem & 15;
            int kg  = ksq * 256 + c * 64 + kq * 4;
            *(float4*)&As[ksq][bb][kq * 4] = *(const float4*)(h1n + (size_t)bb * H_ + kg);
        }
        __syncthreads();

        int kbase = ks * 256 + c * 64;
        const float4* w0 = (const float4*)(w_in + (size_t)j * H_ + kbase);
        const float4* A4 = (const float4*)&As[ks][b][0];
        #pragma unroll
        for (int kk = 0; kk < 16; ++kk) {
            float4 a  = A4[kk];
            float4 q0 = w0[kk];
            acc += a.x * q0.x + a.y * q0.y + a.z * q0.z + a.w * q0.w;
        }
        __syncthreads();
    }

    int idx = tid & 63;
    if (ks > 0) red[ks - 1][idx] = acc;
    __syncthreads();
    if (ks == 0) {
        acc += red[0][idx] + red[1][idx] + red[2][idx];
        q_out[b * H_ + j] = acc;
    }
}

// ---------------------------------------------------------------------------
// scores[b][s] = x[b] . base[b][s]   grid 512 = b(32) x stile(16), block 256.
// Used with (h1n, pmem) on the fast path, (q, mem) on the fallback path.
// ---------------------------------------------------------------------------
__global__ __launch_bounds__(256) void k_scores(
    const float* __restrict__ x_in, const float* __restrict__ base,
    float* __restrict__ sc_out)
{
    __shared__ float q_lds[1024];

    int b  = blockIdx.x >> 4;
    int st = blockIdx.x & 15;
    int tid  = threadIdx.x;
    int lane = tid & 63;
    int wv   = tid >> 6;

    ((float4*)q_lds)[tid] = ((const float4*)(x_in + (size_t)b * H_))[tid];
    __syncthreads();

    float4 q4[4];
    #pragma unroll
    for (int i = 0; i < 4; ++i) q4[i] = ((const float4*)q_lds)[lane + 64 * i];

    const float* mb = base + (size_t)b * S_ * H_;
    #pragma unroll
    for (int ss = 0; ss < 4; ++ss) {
        int s = st * 16 + wv * 4 + ss;
        const float4* mr = (const float4*)(mb + (size_t)s * H_);
        float a = 0.0f;
        #pragma unroll
        for (int i = 0; i < 4; ++i) {
            float4 m = mr[lane + 64 * i];
            a += q4[i].x * m.x + q4[i].y * m.y + q4[i].z * m.z + q4[i].w * m.w;
        }
        #pragma unroll
        for (int o = 32; o > 0; o >>= 1) a += __shfl_down(a, o);
        if (lane == 0) sc_out[b * S_ + s] = a;
    }
}

// ---------------------------------------------------------------------------
// ctx: local masked softmax of scores + weighted sum.  grid 512, block 256
// ---------------------------------------------------------------------------
__global__ __launch_bounds__(256) void k_ctx(
    const float* __restrict__ sc_in, const float* __restrict__ mem,
    const int* __restrict__ masks,
    float* __restrict__ ctx, float* __restrict__ attn_out, int t)
{
    __shared__ float aw[256];
    __shared__ float red2[4][64];

    int b  = blockIdx.x >> 4;
    int ht = blockIdx.x & 15;
    int tid  = threadIdx.x;
    int lane = tid & 63;
    int wv   = tid >> 6;

    if (wv == 0) {
        int m = 0;
        #pragma unroll
        for (int i = 0; i < 4; ++i) m += masks[b * S_ + lane * 4 + i];
        #pragma unroll
        for (int o = 32; o > 0; o >>= 1) m += __shfl_down(m, o);
        int len = __shfl(m, 0);

        float v[4];
        float mx = -1e30f;
        #pragma unroll
        for (int i = 0; i < 4; ++i) {
            int s = lane + 64 * i;
            float xv = (s < len) ? sc_in[b * S_ + s] : -1e9f;
            v[i] = xv;
            mx = fmaxf(mx, xv);
        }
        #pragma unroll
        for (int o = 32; o > 0; o >>= 1) mx = fmaxf(mx, __shfl_xor(mx, o));
        float sm = 0.0f;
        #pragma unroll
        for (int i = 0; i < 4; ++i) { v[i] = __expf(v[i] - mx); sm += v[i]; }
        #pragma unroll
        for (int o = 32; o > 0; o >>= 1) sm += __shfl_xor(sm, o);
        float inv = 1.0f / sm;
        #pragma unroll
        for (int i = 0; i < 4; ++i) {
            int s = lane + 64 * i;
            float w = v[i] * inv;
            aw[s] = w;
            if (ht == 0) attn_out[((size_t)b * T_ + t) * S_ + s] = w;
        }
    }
    __syncthreads();

    int h = ht * 64 + lane;
    const float* mb = mem + (size_t)b * S_ * H_;
    float a = 0.0f;
    #pragma unroll 8
    for (int ss = 0; ss < 64; ++ss) {
        int s = wv * 64 + ss;
        a += aw[s] * mb[(size_t)s * H_ + h];
    }
    red2[wv][lane] = a;
    __syncthreads();
    if (tid < 64) {
        float r = red2[0][tid] + red2[1][tid] + red2[2][tid] + red2[3][tid];
        ctx[b * H_ + ht * 64 + tid] = r;
    }
}

// -------- out = tanh([ctx | h1n] @ w_out^T) --------------------------------
__global__ __launch_bounds__(256) void k_out(
    const float* __restrict__ w_out, const float* __restrict__ ctx,
    const float* __restrict__ h1n,
    float* __restrict__ feedn, float* __restrict__ dout, int t)
{
    __shared__ float As[4][32][68];
    __shared__ float red[3][64];

    int tid = threadIdx.x;
    int b  = tid & 31;
    int jl = (tid >> 5) & 1;
    int ks = tid >> 6;
    int j  = blockIdx.x * 2 + jl;

    float acc = 0.0f;
    for (int c = 0; c < 8; ++c) {
        #pragma unroll
        for (int i = 0; i < 8; ++i) {
            int q   = tid + i * 256;
            int ksq = q >> 9;
            int rem = q & 511;
            int bb  = rem >> 4;
            int kq  = rem & 15;
            int kg  = ksq * 512 + c * 64 + kq * 4;
            const float* src = (kg < 1024) ? (ctx + (size_t)bb * H_ + kg)
                                           : (h1n + (size_t)bb * H_ + (kg - 1024));
            *(float4*)&As[ksq][bb][kq * 4] = *(const float4*)src;
        }
        __syncthreads();

        int kbase = ks * 512 + c * 64;
        const float4* w0 = (const float4*)(w_out + (size_t)j * 2048 + kbase);
        const float4* A4 = (const float4*)&As[ks][b][0];
        #pragma unroll
        for (int kk = 0; kk < 16; ++kk) {
            float4 a  = A4[kk];
            float4 q0 = w0[kk];
            acc += a.x * q0.x + a.y * q0.y + a.z * q0.z + a.w * q0.w;
        }
        __syncthreads();
    }

    int idx = tid & 63;
    if (ks > 0) red[ks - 1][idx] = acc;
    __syncthreads();
    if (ks == 0) {
        acc += red[0][idx] + red[1][idx] + red[2][idx];
        float o = tanh_(acc);
        feedn[b * H_ + j] = o;
        dout[((size_t)b * T_ + t) * H_ + j] = o;
    }
}

// ---------------------------------------------------------------------------
extern "C" void kernel_launch(void* const* d_in, const int* in_sizes, int n_in,
                              void* d_out, int out_size, void* d_ws, size_t ws_size,
                              hipStream_t stream) {
    const int*   tgt    = (const int*)  d_in[0];
    const float* mem    = (const float*)d_in[1];
    const int*   masks  = (const int*)  d_in[2];
    const float* h0in   = (const float*)d_in[3];
    const float* c0in   = (const float*)d_in[4];
    const float* emb    = (const float*)d_in[5];
    const float* w_ih0  = (const float*)d_in[6];
    const float* w_hh0  = (const float*)d_in[7];
    const float* b_ih0  = (const float*)d_in[8];
    const float* b_hh0  = (const float*)d_in[9];
    const float* w_ih1  = (const float*)d_in[10];
    const float* w_hh1  = (const float*)d_in[11];
    const float* b_ih1  = (const float*)d_in[12];
    const float* b_hh1  = (const float*)d_in[13];
    const float* w_in   = (const float*)d_in[14];
    const float* w_out  = (const float*)d_in[15];

    float* dout     = (float*)d_out;
    float* attn_out = dout + (size_t)B_ * T_ * H_;

    float* ws   = (float*)d_ws;
    float* h0s  = ws;              // [2][B*H]
    float* c0s  = h0s  + 2 * BH_;  // [2][B*H]
    float* h1s  = c0s  + 2 * BH_;  // [2][B*H]
    float* c1s  = h1s  + 2 * BH_;  // [2][B*H]
    float* feed = c1s  + 2 * BH_;  // [2][B*H]
    float* qctx = feed + 2 * BH_;  // [B*H]   (ctx; fallback also uses as q)
    float* scw  = qctx + BH_;      // [B*S]
    float* pmem = scw  + B_ * S_;  // [B*S*H] = 33.5 MB

    const size_t need = ((size_t)(11 * BH_ + B_ * S_) + (size_t)B_ * S_ * H_) * 4;
    const bool use_pmem = (ws_size >= need);

    k_init<<<128, 256, 0, stream>>>(h0in, c0in, h0s, c0s, h1s, c1s, feed);

    if (use_pmem) {
        // one-time projected memory: pmem[b,s,:] = mem[b,s,:] @ w_in
        k_pmem<<<dim3(128, 16), 256, 0, stream>>>(mem, w_in, pmem);

        for (int t = 0; t < T_; ++t) {
            int cur = t & 1, nxt = cur ^ 1;
            k_lstm0<<<512, 256, 0, stream>>>(tgt, emb, w_ih0, w_hh0, b_ih0, b_hh0,
                                             feed + cur * BH_, h0s + cur * BH_, c0s + cur * BH_,
                                             h0s + nxt * BH_, c0s + nxt * BH_, t);
            k_lstm1<<<512, 256, 0, stream>>>(w_ih1, w_hh1, b_ih1, b_hh1,
                                             h0s + nxt * BH_, h1s + cur * BH_, c1s + cur * BH_,
                                             h1s + nxt * BH_, c1s + nxt * BH_);
            k_scores<<<512, 256, 0, stream>>>(h1s + nxt * BH_, pmem, scw);
            k_ctx<<<512, 256, 0, stream>>>(scw, mem, masks, qctx, attn_out, t);
            k_out<<<512, 256, 0, stream>>>(w_out, qctx, h1s + nxt * BH_,
                                           feed + nxt * BH_, dout, t);
        }
    } else {
        // fallback: full round-2 pipeline (q computed per step)
        for (int t = 0; t < T_; ++t) {
            int cur = t & 1, nxt = cur ^ 1;
            k_lstm0<<<512, 256, 0, stream>>>(tgt, emb, w_ih0, w_hh0, b_ih0, b_hh0,
                                             feed + cur * BH_, h0s + cur * BH_, c0s + cur * BH_,
                                             h0s + nxt * BH_, c0s + nxt * BH_, t);
            k_lstm1<<<512, 256, 0, stream>>>(w_ih1, w_hh1, b_ih1, b_hh1,
                                             h0s + nxt * BH_, h1s + cur * BH_, c1s + cur * BH_,
                                             h1s + nxt * BH_, c1s + nxt * BH_);
            k_q<<<512, 256, 0, stream>>>(w_in, h1s + nxt * BH_, qctx);
            k_scores<<<512, 256, 0, stream>>>(qctx, mem, scw);
            k_ctx<<<512, 256, 0, stream>>>(scw, mem, masks, qctx, attn_out, t);
            k_out<<<512, 256, 0, stream>>>(w_out, qctx, h1s + nxt * BH_,
                                           feed + nxt * BH_, dout, t);
        }
    }
}